// Round 5
// baseline (650.066 us; speedup 1.0000x reference)
//
#include <hip/hip_runtime.h>
#include <math.h>

// PolylineNet v5: wave-autonomous. One wave = one polyline, no __syncthreads
// in the main kernel. LN/pool fully in-wave (shfl_xor over l15 / lg).
// Pooled-concat = K=256 GEMM with broadcast pooled fragment from LDS.
// Head (M=1-row GEMMs) split into kernel 2 (M=64 tiles); pooled2+valid
// passed via d_out cols [0..128] of each 256-col row.

#define PP 20
#define HH 128
#define OO 256
#define HSTR 132       // LDS row stride in halves (264 B)
#define NW 4           // waves per block

typedef _Float16 f16x4 __attribute__((ext_vector_type(4)));
typedef _Float16 f16x8 __attribute__((ext_vector_type(8)));
typedef float    f32x4 __attribute__((ext_vector_type(4)));

__device__ __forceinline__ f32x4 splat4(float x) { f32x4 v = {x, x, x, x}; return v; }

__device__ __forceinline__ f16x8 ldfrag(const _Float16* p)
{
  f16x8 r;
  f16x4* r4 = reinterpret_cast<f16x4*>(&r);
  r4[0] = *reinterpret_cast<const f16x4*>(p);
  r4[1] = *reinterpret_cast<const f16x4*>(p + 16);
  return r;
}

__device__ __forceinline__ f32x4 MFMA(f16x8 a, f16x8 b, f32x4 c)
{
  return __builtin_amdgcn_mfma_f32_16x16x32_f16(a, b, c, 0, 0, 0);
}

__device__ __forceinline__ void zacc(f32x4 acc[2][8])
{
#pragma unroll
  for (int mt = 0; mt < 2; mt++)
#pragma unroll
    for (int nt = 0; nt < 8; nt++) acc[mt][nt] = splat4(0.f);
}

// Per-wave GEMM: acc[2][8] += A[32 rows x K] @ Wt[N=128][KLD].
// A k-range [0, 32*KS_H) from Hw rows; [32*KS_H, 32*(KS_H+KS_P)) from the
// pooled vector Pw (row-independent broadcast fragments).
template<int KS_H, int KS_P, int KLD>
__device__ __forceinline__ void wgemm(const _Float16* __restrict__ Hw,
                                      const _Float16* __restrict__ Pw,
                                      const _Float16* __restrict__ Wt,
                                      f32x4 acc[2][8], int l15, int lg)
{
  f16x8 a0[KS_H], a1[KS_H];
#pragma unroll
  for (int ks = 0; ks < KS_H; ks++) {
    a0[ks] = ldfrag(Hw + l15 * HSTR + 4 * lg + 32 * ks);
    a1[ks] = ldfrag(Hw + (16 + l15) * HSTR + 4 * lg + 32 * ks);
  }
  f16x8 ap[KS_P ? KS_P : 1];
#pragma unroll
  for (int ks = 0; ks < KS_P; ks++)
    ap[ks] = ldfrag(Pw + 4 * lg + 32 * ks);
#pragma unroll
  for (int nt = 0; nt < 8; nt++) {
    const _Float16* bp = Wt + (size_t)(nt * 16 + l15) * KLD + 4 * lg;
#pragma unroll
    for (int ks = 0; ks < KS_H; ks++) {
      f16x8 b = ldfrag(bp + 32 * ks);
      acc[0][nt] = MFMA(a0[ks], b, acc[0][nt]);
      acc[1][nt] = MFMA(a1[ks], b, acc[1][nt]);
    }
#pragma unroll
    for (int ks = 0; ks < KS_P; ks++) {
      f16x8 b = ldfrag(bp + 32 * (KS_H + ks));
      acc[0][nt] = MFMA(ap[ks], b, acc[0][nt]);
      acc[1][nt] = MFMA(ap[ks], b, acc[1][nt]);
    }
  }
}

// In-wave LayerNorm over acc[2][8] (rows = 16*mt+4*lg+j, cols = 16*nt+l15).
// Row stats via 4x shfl_xor over l15. Optional mask-select (also kills
// rows >= 20), optional in-register pool (requires DOMASK), optional
// fp16 writeback of all 32 rows (masked stages write 0 to rows >= 20).
template<bool ADDB, bool DOMASK, bool DOPOOL, bool DOWRITE>
__device__ __forceinline__ void ln_wave(f32x4 acc[2][8],
                                        const float* __restrict__ bias,
                                        const float* __restrict__ gamma,
                                        const float* __restrict__ beta,
                                        const float mfs[8],
                                        _Float16* __restrict__ Hw,
                                        float pooled[8], int l15, int lg)
{
  float bb[8], gg[8], be[8];
#pragma unroll
  for (int nt = 0; nt < 8; nt++) {
    const int c = nt * 16 + l15;
    bb[nt] = ADDB ? bias[c] : 0.f;
    gg[nt] = gamma[c];
    be[nt] = beta[c];
  }
#pragma unroll
  for (int mt = 0; mt < 2; mt++) {
#pragma unroll
    for (int j = 0; j < 4; j++) {
      const int row = mt * 16 + lg * 4 + j;
      float s = 0.f, q = 0.f;
#pragma unroll
      for (int nt = 0; nt < 8; nt++) {
        float v = acc[mt][nt][j] + bb[nt];
        acc[mt][nt][j] = v;
        s += v;
        q = fmaf(v, v, q);
      }
#pragma unroll
      for (int off = 1; off < 16; off <<= 1) {
        s += __shfl_xor(s, off, 64);
        q += __shfl_xor(q, off, 64);
      }
      const float mu = s * (1.0f / HH);
      const float rs = rsqrtf(q * (1.0f / HH) - mu * mu + 1e-5f);
      const float m = mfs[mt * 4 + j];
#pragma unroll
      for (int nt = 0; nt < 8; nt++) {
        float v = fmaxf(fmaf((acc[mt][nt][j] - mu) * rs, gg[nt], be[nt]), 0.f);
        if (DOMASK) v = (m != 0.f) ? v : 0.f;   // select: kills mask-0, rows>=20, NaN
        if (DOPOOL) pooled[nt] = fmaxf(pooled[nt], v);
        if (DOWRITE) Hw[row * HSTR + nt * 16 + l15] = (_Float16)v;
      }
    }
  }
}

// ---- prep: transpose+convert all weights to fp16 [N][K] into d_ws ----
// layout (halves): W1t[128][32] @0 | W2t[128][128] @4096 | F2W1cat[128][256] @20480
//                | F2W2t[128][128] @53248 | FOW1t[128][128] @69632 | FOW2t[256][128] @86016
__global__ void prep_weights(const float* __restrict__ W1, const float* __restrict__ W2,
                             const float* __restrict__ F2W1, const float* __restrict__ F2W2,
                             const float* __restrict__ FO1, const float* __restrict__ FO2,
                             _Float16* __restrict__ wt)
{
  const int idx = blockIdx.x * 256 + threadIdx.x;
  if (idx >= 118784) return;
  float v;
  if (idx < 4096)        { int n = idx >> 5, k = idx & 31;            v = (k < 13) ? W1[k * 128 + n] : 0.f; }
  else if (idx < 20480)  { int j = idx - 4096;  int n = j >> 7, k = j & 127; v = W2[k * 128 + n]; }
  else if (idx < 53248)  { int j = idx - 20480; int n = j >> 8, k = j & 255; v = F2W1[k * 128 + n]; }
  else if (idx < 69632)  { int j = idx - 53248; int n = j >> 7, k = j & 127; v = F2W2[k * 128 + n]; }
  else if (idx < 86016)  { int j = idx - 69632; int n = j >> 7, k = j & 127; v = FO1[k * 128 + n]; }
  else                   { int j = idx - 86016; int n = j >> 7, k = j & 127; v = FO2[k * 256 + n]; }
  wt[idx] = (_Float16)v;
}

// ---- main kernel: barrier-free, 1 wave = 1 polyline ----
extern "C" __global__ void __launch_bounds__(256)
polynet_main(const float* __restrict__ poly, const int* __restrict__ maskp,
             const float* __restrict__ b1,  const float* __restrict__ g1,  const float* __restrict__ be1,
             const float* __restrict__ b2,  const float* __restrict__ g2,  const float* __restrict__ be2,
             const float* __restrict__ f2b1, const float* __restrict__ f2g1, const float* __restrict__ f2be1,
             const float* __restrict__ f2b2, const float* __restrict__ f2g2, const float* __restrict__ f2be2,
             const _Float16* __restrict__ wt, float* __restrict__ out)
{
  __shared__ _Float16 HhA[NW][32 * HSTR];   // per-wave activation tiles
  __shared__ _Float16 PA[NW][HH];           // per-wave pooled vector

  const int tid  = threadIdx.x;
  const int lane = tid & 63;
  const int w    = tid >> 6;
  const int l15  = lane & 15;
  const int lg   = lane >> 4;
  const int pid  = blockIdx.x * NW + w;     // polyline id

  _Float16* Hw = &HhA[w][0];
  _Float16* Pw = &PA[w][0];

  // zero rows 0..31, k 0..31 (covers GEMM1's K range incl. pad rows)
#pragma unroll
  for (int it = 0; it < 8; it++) {
    const int idx = it * 64 + lane;          // 0..511 u32 slots
    const int r = idx >> 4, kp = idx & 15;
    *reinterpret_cast<unsigned int*>(Hw + r * HSTR + 2 * kp) = 0u;
  }
  // stage X: rows 0..19, k 0..12
  const float* xp = poly + (size_t)pid * (PP * 13);
#pragma unroll
  for (int it = 0; it < 5; it++) {
    const int idx = it * 64 + lane;
    if (idx < PP * 13) {
      const int r = idx / 13, k = idx % 13;
      Hw[r * HSTR + k] = (_Float16)xp[idx];
    }
  }
  // mask -> per-slot floats + valid flag (all in-wave)
  int mrow = 0;
  if (lane < PP) mrow = maskp[(size_t)pid * PP + lane];
  const unsigned long long bal = __ballot(lane < PP && mrow != 0);
  const float vld = bal ? 1.f : 0.f;
  float mfs[8];
#pragma unroll
  for (int mt = 0; mt < 2; mt++)
#pragma unroll
    for (int j = 0; j < 4; j++) {
      const int row = mt * 16 + lg * 4 + j;
      const int mm = __shfl(mrow, row, 64);
      mfs[mt * 4 + j] = (row < PP && mm != 0) ? 1.f : 0.f;
    }

  f32x4 acc[2][8];
  float pooled[8];

  // ---- fc1 linear1 (K=32) + LN1 ----
  zacc(acc);
  wgemm<1, 0, 32>(Hw, Pw, wt, acc, l15, lg);
  ln_wave<true, false, false, true>(acc, b1, g1, be1, mfs, Hw, pooled, l15, lg);

  // ---- fc1 linear2 (K=128) + LN2 (mask, pool, write) ----
  zacc(acc);
  wgemm<4, 0, 128>(Hw, Pw, wt + 4096, acc, l15, lg);
#pragma unroll
  for (int nt = 0; nt < 8; nt++) pooled[nt] = 0.f;
  ln_wave<true, true, true, true>(acc, b2, g2, be2, mfs, Hw, pooled, l15, lg);
#pragma unroll
  for (int nt = 0; nt < 8; nt++) {
    pooled[nt] = fmaxf(pooled[nt], __shfl_xor(pooled[nt], 16, 64));
    pooled[nt] = fmaxf(pooled[nt], __shfl_xor(pooled[nt], 32, 64));
  }
  if (lg == 0) {
#pragma unroll
    for (int nt = 0; nt < 8; nt++) Pw[nt * 16 + l15] = (_Float16)pooled[nt];
  }

  // ---- fc2 linear1 as K=256 (feat from Hw, pooled from Pw) + LN3 ----
  zacc(acc);
  wgemm<4, 4, 256>(Hw, Pw, wt + 20480, acc, l15, lg);
  ln_wave<true, false, false, true>(acc, f2b1, f2g1, f2be1, mfs, Hw, pooled, l15, lg);

  // ---- fc2 linear2 (K=128) + LN4 (mask, pool, no write) ----
  zacc(acc);
  wgemm<4, 0, 128>(Hw, Pw, wt + 53248, acc, l15, lg);
#pragma unroll
  for (int nt = 0; nt < 8; nt++) pooled[nt] = 0.f;
  ln_wave<true, true, true, false>(acc, f2b2, f2g2, f2be2, mfs, Hw, pooled, l15, lg);
#pragma unroll
  for (int nt = 0; nt < 8; nt++) {
    pooled[nt] = fmaxf(pooled[nt], __shfl_xor(pooled[nt], 16, 64));
    pooled[nt] = fmaxf(pooled[nt], __shfl_xor(pooled[nt], 32, 64));
  }

  // ---- stash pooled2 (f32) + valid into out row [pid][0..128] ----
  if (lg == 0) {
    float* op = out + (size_t)pid * OO;
#pragma unroll
    for (int nt = 0; nt < 8; nt++) op[nt * 16 + l15] = pooled[nt];
    if (l15 == 0) op[HH] = vld;
  }
}

// ---- kernel 2: head over pooled2. Block = 64 rows, 4 waves. ----
extern "C" __global__ void __launch_bounds__(256)
polynet_head(float* __restrict__ out, const _Float16* __restrict__ wt,
             const float* __restrict__ fob1, const float* __restrict__ fob2)
{
  __shared__ _Float16 Z0[64 * HSTR];
  __shared__ _Float16 Z1[64 * HSTR];
  __shared__ float    vldv[64];

  const int tid  = threadIdx.x;
  const int lane = tid & 63;
  const int w    = tid >> 6;
  const int l15  = lane & 15;
  const int lg   = lane >> 4;
  const int rbase = blockIdx.x * 64;

  const _Float16* FOW1t = wt + 69632;
  const _Float16* FOW2t = wt + 86016;

  // stage pooled2 + valid (before any writes to these rows)
  for (int i = tid; i < 64 * HH; i += 256) {
    const int r = i >> 7, c = i & 127;
    Z0[r * HSTR + c] = (_Float16)out[(size_t)(rbase + r) * OO + c];
  }
  if (tid < 64) vldv[tid] = out[(size_t)(rbase + tid) * OO + HH];
  __syncthreads();

  // z = relu(pooled2 @ FOW1 + fob1): wave w owns cols 32w..32w+31 (nt 2w,2w+1)
  {
    f32x4 az[4][2];
    const float bz0 = fob1[32 * w + l15];
    const float bz1 = fob1[32 * w + 16 + l15];
#pragma unroll
    for (int mt = 0; mt < 4; mt++) { az[mt][0] = splat4(bz0); az[mt][1] = splat4(bz1); }
    f16x8 bfr[2][4];
#pragma unroll
    for (int nt = 0; nt < 2; nt++) {
      const _Float16* bp = FOW1t + (size_t)((2 * w + nt) * 16 + l15) * 128 + 4 * lg;
#pragma unroll
      for (int ks = 0; ks < 4; ks++) bfr[nt][ks] = ldfrag(bp + 32 * ks);
    }
#pragma unroll
    for (int mt = 0; mt < 4; mt++) {
#pragma unroll
      for (int ks = 0; ks < 4; ks++) {
        f16x8 a = ldfrag(Z0 + (mt * 16 + l15) * HSTR + 4 * lg + 32 * ks);
        az[mt][0] = MFMA(a, bfr[0][ks], az[mt][0]);
        az[mt][1] = MFMA(a, bfr[1][ks], az[mt][1]);
      }
    }
#pragma unroll
    for (int mt = 0; mt < 4; mt++)
#pragma unroll
      for (int j = 0; j < 4; j++) {
        const int row = mt * 16 + lg * 4 + j;
        Z1[row * HSTR + 32 * w + l15]      = (_Float16)fmaxf(az[mt][0][j], 0.f);
        Z1[row * HSTR + 32 * w + 16 + l15] = (_Float16)fmaxf(az[mt][1][j], 0.f);
      }
  }
  __syncthreads();

  // out = (z @ FOW2 + fob2) * valid: wave w owns cols 64w..64w+63 (nt 4w..4w+3)
  {
    f16x8 a[4][4];
#pragma unroll
    for (int mt = 0; mt < 4; mt++)
#pragma unroll
      for (int ks = 0; ks < 4; ks++)
        a[mt][ks] = ldfrag(Z1 + (mt * 16 + l15) * HSTR + 4 * lg + 32 * ks);
    f32x4 o[4][4];
#pragma unroll
    for (int nt = 0; nt < 4; nt++) {
      const int c = (4 * w + nt) * 16 + l15;
      const float bo = fob2[c];
#pragma unroll
      for (int mt = 0; mt < 4; mt++) o[mt][nt] = splat4(bo);
      const _Float16* bp = FOW2t + (size_t)((4 * w + nt) * 16 + l15) * 128 + 4 * lg;
#pragma unroll
      for (int ks = 0; ks < 4; ks++) {
        f16x8 b = ldfrag(bp + 32 * ks);
#pragma unroll
        for (int mt = 0; mt < 4; mt++) o[mt][nt] = MFMA(a[mt][ks], b, o[mt][nt]);
      }
    }
#pragma unroll
    for (int mt = 0; mt < 4; mt++)
#pragma unroll
      for (int j = 0; j < 4; j++) {
        const int row = mt * 16 + lg * 4 + j;
        const float v = vldv[row];
#pragma unroll
        for (int nt = 0; nt < 4; nt++)
          out[(size_t)(rbase + row) * OO + (4 * w + nt) * 16 + l15] = o[mt][nt][j] * v;
      }
  }
}

extern "C" void kernel_launch(void* const* d_in, const int* in_sizes, int n_in,
                              void* d_out, int out_size, void* d_ws, size_t ws_size,
                              hipStream_t stream)
{
  const float* poly  = (const float*)d_in[0];
  const int*   mask  = (const int*)d_in[1];
  const float* W1    = (const float*)d_in[2];
  const float* b1    = (const float*)d_in[3];
  const float* g1    = (const float*)d_in[4];
  const float* be1   = (const float*)d_in[5];
  const float* W2    = (const float*)d_in[6];
  const float* b2    = (const float*)d_in[7];
  const float* g2    = (const float*)d_in[8];
  const float* be2   = (const float*)d_in[9];
  const float* f2W1  = (const float*)d_in[10];
  const float* f2b1  = (const float*)d_in[11];
  const float* f2g1  = (const float*)d_in[12];
  const float* f2be1 = (const float*)d_in[13];
  const float* f2W2  = (const float*)d_in[14];
  const float* f2b2  = (const float*)d_in[15];
  const float* f2g2  = (const float*)d_in[16];
  const float* f2be2 = (const float*)d_in[17];
  const float* foW1  = (const float*)d_in[18];
  const float* fob1  = (const float*)d_in[19];
  const float* foW2  = (const float*)d_in[20];
  const float* fob2  = (const float*)d_in[21];
  float* out = (float*)d_out;

  _Float16* wt = (_Float16*)d_ws;   // 237,568 B fp16 weights

  prep_weights<<<dim3((118784 + 255) / 256), dim3(256), 0, stream>>>(
      W1, W2, f2W1, f2W2, foW1, foW2, wt);

  const int npoly = in_sizes[0] / (PP * 13);   // 16384

  polynet_main<<<dim3(npoly / NW), dim3(256), 0, stream>>>(
      poly, mask, b1, g1, be1, b2, g2, be2,
      f2b1, f2g1, f2be1, f2b2, f2g2, f2be2, wt, out);

  polynet_head<<<dim3(npoly / 64), dim3(256), 0, stream>>>(out, wt, fob1, fob2);
}

// Round 6
// 533.793 us; speedup vs baseline: 1.2178x; 1.2178x over previous
//
#include <hip/hip_runtime.h>
#include <math.h>

// PolylineNet v6: layer-by-layer GEMM kernels, activations in d_ws (fp16),
// LN fused as epilogue (R2-proven code). A-fragments direct from global
// (LLC-resident), B-fragments from pre-transposed fp16 weights.
// Fallback to fp32 fused kernel (R1, proven) if ws_size is insufficient.

#define PP 20
#define HH 128
#define OO 256
#define MM 160         // rows per block (8 polylines)
#define MT 10          // M-tiles of 16
#define GG 8           // polylines per block
#define PSTR 136       // LDS stride (halves) for small staged tiles, 16B-aligned
#define XSTR 40        // LDS stride (halves) for the X tile

typedef _Float16 f16x4 __attribute__((ext_vector_type(4)));
typedef _Float16 f16x8 __attribute__((ext_vector_type(8)));
typedef float    f32x4 __attribute__((ext_vector_type(4)));

__device__ __forceinline__ f32x4 splat4(float x) { f32x4 v = {x, x, x, x}; return v; }

__device__ __forceinline__ f16x8 ldfrag(const _Float16* p)
{
  f16x8 r;
  f16x4* r4 = reinterpret_cast<f16x4*>(&r);
  r4[0] = *reinterpret_cast<const f16x4*>(p);
  r4[1] = *reinterpret_cast<const f16x4*>(p + 16);
  return r;
}

__device__ __forceinline__ f32x4 MFMA(f16x8 a, f16x8 b, f32x4 c)
{
  return __builtin_amdgcn_mfma_f32_16x16x32_f16(a, b, c, 0, 0, 0);
}

// GEMM, A read directly from GLOBAL (dense rows of 128 halves).
// acc[mt][nt] += A[160 x 32*KSTEPS] @ Wt[N=128][KLD]; wave w owns nt {2w,2w+1}.
template<int KSTEPS, int KLD, bool INIT0>
__device__ __forceinline__ void gemm_g(const _Float16* __restrict__ Ag,
                                       const _Float16* __restrict__ Wt,
                                       f32x4 acc[MT][2], int l15, int lg, int w)
{
  f16x8 bfr[2][KSTEPS];
#pragma unroll
  for (int nt = 0; nt < 2; nt++) {
    const _Float16* bp = Wt + (size_t)((2 * w + nt) * 16 + l15) * KLD + 4 * lg;
#pragma unroll
    for (int ks = 0; ks < KSTEPS; ks++) bfr[nt][ks] = ldfrag(bp + 32 * ks);
  }
#pragma unroll
  for (int mt = 0; mt < MT; mt++) {
    if (INIT0) { acc[mt][0] = splat4(0.f); acc[mt][1] = splat4(0.f); }
    const _Float16* ap = Ag + (size_t)(mt * 16 + l15) * HH + 4 * lg;
#pragma unroll
    for (int ks = 0; ks < KSTEPS; ks++) {
      f16x8 af = ldfrag(ap + 32 * ks);
      acc[mt][0] = MFMA(af, bfr[0][ks], acc[mt][0]);
      acc[mt][1] = MFMA(af, bfr[1][ks], acc[mt][1]);
    }
  }
}

// GEMM, A from LDS with stride astr (for the X tile).
template<int KSTEPS, int KLD, bool INIT0>
__device__ __forceinline__ void gemm_l(const _Float16* __restrict__ Ah, int astr,
                                       const _Float16* __restrict__ Wt,
                                       f32x4 acc[MT][2], int l15, int lg, int w)
{
  f16x8 bfr[2][KSTEPS];
#pragma unroll
  for (int nt = 0; nt < 2; nt++) {
    const _Float16* bp = Wt + (size_t)((2 * w + nt) * 16 + l15) * KLD + 4 * lg;
#pragma unroll
    for (int ks = 0; ks < KSTEPS; ks++) bfr[nt][ks] = ldfrag(bp + 32 * ks);
  }
#pragma unroll
  for (int mt = 0; mt < MT; mt++) {
    if (INIT0) { acc[mt][0] = splat4(0.f); acc[mt][1] = splat4(0.f); }
    const _Float16* ap = Ah + (mt * 16 + l15) * astr + 4 * lg;
#pragma unroll
    for (int ks = 0; ks < KSTEPS; ks++) {
      f16x8 af = ldfrag(ap + 32 * ks);
      acc[mt][0] = MFMA(af, bfr[0][ks], acc[mt][0]);
      acc[mt][1] = MFMA(af, bfr[1][ks], acc[mt][1]);
    }
  }
}

// Single-M-tile GEMM (A = 16 rows in LDS, stride astr), 2 N-tiles at ntbase.
template<int KSTEPS, int KLD>
__device__ __forceinline__ void gemm16(const _Float16* __restrict__ Ah, int astr,
                                       const _Float16* __restrict__ Wt,
                                       f32x4* acc, int l15, int lg, int ntbase)
{
  f16x8 af[KSTEPS];
#pragma unroll
  for (int ks = 0; ks < KSTEPS; ks++)
    af[ks] = ldfrag(Ah + l15 * astr + 4 * lg + 32 * ks);
#pragma unroll
  for (int nt = 0; nt < 2; nt++) {
    const _Float16* bp = Wt + (size_t)((ntbase + nt) * 16 + l15) * KLD + 4 * lg;
#pragma unroll
    for (int ks = 0; ks < KSTEPS; ks++) {
      f16x8 bf = ldfrag(bp + 32 * ks);
      acc[nt] = MFMA(af[ks], bf, acc[nt]);
    }
  }
}

// LN partials: optional bias add, then per-row {sum, sumsq} -> part (R2-proven).
template<bool ADDB>
__device__ __forceinline__ void ln_partials(f32x4 acc[MT][2], const float* __restrict__ bias,
                                            float2* __restrict__ part, int l15, int lg, int w)
{
  float bb0 = 0.f, bb1 = 0.f;
  if (ADDB) { bb0 = bias[32 * w + l15]; bb1 = bias[32 * w + 16 + l15]; }
#pragma unroll
  for (int mt = 0; mt < MT; mt++) {
#pragma unroll
    for (int j = 0; j < 4; j++) {
      if (ADDB) { acc[mt][0][j] += bb0; acc[mt][1][j] += bb1; }
      float s = acc[mt][0][j] + acc[mt][1][j];
      float q = acc[mt][0][j] * acc[mt][0][j] + acc[mt][1][j] * acc[mt][1][j];
#pragma unroll
      for (int off = 1; off < 16; off <<= 1) {
        s += __shfl_xor(s, off, 64);
        q += __shfl_xor(q, off, 64);
      }
      if (l15 == 0) part[(mt * 16 + lg * 4 + j) * 4 + w] = make_float2(s, q);
    }
  }
}

// Normalize with inlined stats (reads all 4 wave-partials from part; safe here:
// one LN per kernel so no WAR reuse of part). Optional mask / pool / global write.
template<bool DOMASK, bool DOPOOL, bool DOWRITE>
__device__ __forceinline__ void ln_norm_g(f32x4 acc[MT][2],
                                          const float* __restrict__ gamma,
                                          const float* __restrict__ beta,
                                          const float* __restrict__ mf,
                                          int* __restrict__ pmaxI,
                                          _Float16* __restrict__ Hout,  // + blk row base
                                          const float2* __restrict__ part,
                                          int l15, int lg, int w)
{
  const int c0 = 32 * w + l15, c1 = c0 + 16;
  const float gg0 = gamma[c0], be0 = beta[c0];
  const float gg1 = gamma[c1], be1 = beta[c1];
#pragma unroll
  for (int mt = 0; mt < MT; mt++) {
#pragma unroll
    for (int j = 0; j < 4; j++) {
      const int row = mt * 16 + lg * 4 + j;
      float2 p0 = part[row * 4 + 0], p1 = part[row * 4 + 1];
      float2 p2 = part[row * 4 + 2], p3 = part[row * 4 + 3];
      const float s = (p0.x + p1.x) + (p2.x + p3.x);
      const float q = (p0.y + p1.y) + (p2.y + p3.y);
      const float mu  = s * (1.0f / HH);
      const float rs  = rsqrtf(q * (1.0f / HH) - mu * mu + 1e-5f);
      float v0 = fmaxf(fmaf((acc[mt][0][j] - mu) * rs, gg0, be0), 0.f);
      float v1 = fmaxf(fmaf((acc[mt][1][j] - mu) * rs, gg1, be1), 0.f);
      if (DOMASK) { const float m = mf[row]; v0 *= m; v1 *= m; }
      if (DOWRITE) {
        Hout[(size_t)row * HH + c0] = (_Float16)v0;
        Hout[(size_t)row * HH + c1] = (_Float16)v1;
      }
      if (DOPOOL) {
        const int p = (unsigned)row / 20u;
        atomicMax(&pmaxI[p * HH + c0], __float_as_int(v0));
        atomicMax(&pmaxI[p * HH + c1], __float_as_int(v1));
      }
    }
  }
}

// ---- prep: transpose+convert all weights to fp16 [N][K] into ws (R4-proven) ----
__global__ void prep_weights(const float* __restrict__ W1, const float* __restrict__ W2,
                             const float* __restrict__ F2W1, const float* __restrict__ F2W2,
                             const float* __restrict__ FO1, const float* __restrict__ FO2,
                             _Float16* __restrict__ wt)
{
  const int idx = blockIdx.x * 256 + threadIdx.x;
  if (idx >= 118784) return;
  float v;
  if (idx < 4096)        { int n = idx >> 5, k = idx & 31;            v = (k < 13) ? W1[k * 128 + n] : 0.f; }
  else if (idx < 20480)  { int j = idx - 4096;  int n = j >> 7, k = j & 127; v = W2[k * 128 + n]; }
  else if (idx < 36864)  { int j = idx - 20480; int n = j >> 7, k = j & 127; v = F2W1[k * 128 + n]; }
  else if (idx < 53248)  { int j = idx - 36864; int n = j >> 7, k = j & 127; v = F2W1[(128 + k) * 128 + n]; }
  else if (idx < 69632)  { int j = idx - 53248; int n = j >> 7, k = j & 127; v = F2W2[k * 128 + n]; }
  else if (idx < 86016)  { int j = idx - 69632; int n = j >> 7, k = j & 127; v = FO1[k * 128 + n]; }
  else                   { int j = idx - 86016; int n = j >> 7, k = j & 127; v = FO2[k * 256 + n]; }
  wt[idx] = (_Float16)v;
}

// ---- K2: H1 = LN1(X @ W1 + b1) ----
extern "C" __global__ void __launch_bounds__(256, 4)
k_l1(const float* __restrict__ poly, const _Float16* __restrict__ wt,
     const float* __restrict__ b1, const float* __restrict__ g1, const float* __restrict__ be1,
     _Float16* __restrict__ H1)
{
  __shared__ _Float16 Xh[MM * XSTR];
  __shared__ float2   part[MM * 4];
  const int tid = threadIdx.x, lane = tid & 63, w = tid >> 6;
  const int l15 = lane & 15, lg = lane >> 4, blk = blockIdx.x;

  const float* xp = poly + (size_t)blk * (MM * 13);
  for (int i = tid; i < MM * 13; i += 256) {
    const int r = i / 13, k = i % 13;
    Xh[r * XSTR + k] = (_Float16)xp[i];
  }
  for (int i = tid; i < MM * 19; i += 256) {        // zero k = 13..31
    const int r = i / 19, k = 13 + i % 19;
    Xh[r * XSTR + k] = (_Float16)0.f;
  }
  __syncthreads();

  f32x4 acc[MT][2];
  gemm_l<1, 32, true>(Xh, XSTR, wt, acc, l15, lg, w);
  ln_partials<true>(acc, b1, part, l15, lg, w);
  __syncthreads();
  ln_norm_g<false, false, true>(acc, g1, be1, nullptr, nullptr,
                                H1 + (size_t)blk * MM * HH, part, l15, lg, w);
}

// ---- K3: H2 = LN2(H1 @ W2 + b2) * mask; pooled = max_P(H2) ----
extern "C" __global__ void __launch_bounds__(256, 4)
k_l2(const _Float16* __restrict__ H1, const int* __restrict__ maskp,
     const _Float16* __restrict__ wt,
     const float* __restrict__ b2, const float* __restrict__ g2, const float* __restrict__ be2,
     _Float16* __restrict__ H2, _Float16* __restrict__ pooledh)
{
  __shared__ float2 part[MM * 4];
  __shared__ int    pmaxI[GG * HH];
  __shared__ float  mf[MM];
  const int tid = threadIdx.x, lane = tid & 63, w = tid >> 6;
  const int l15 = lane & 15, lg = lane >> 4, blk = blockIdx.x;

  const int* mp = maskp + (size_t)blk * MM;
  for (int i = tid; i < MM; i += 256) mf[i] = mp[i] ? 1.f : 0.f;
  for (int i = tid; i < GG * HH; i += 256) pmaxI[i] = 0;

  f32x4 acc[MT][2];
  gemm_g<4, 128, true>(H1 + (size_t)blk * MM * HH, wt + 4096, acc, l15, lg, w);
  ln_partials<true>(acc, b2, part, l15, lg, w);
  __syncthreads();
  ln_norm_g<true, true, true>(acc, g2, be2, mf, pmaxI,
                              H2 + (size_t)blk * MM * HH, part, l15, lg, w);
  __syncthreads();
  for (int i = tid; i < GG * HH; i += 256)
    pooledh[(size_t)(blk * GG) * HH + i] = (_Float16)__int_as_float(pmaxI[i]);
}

// ---- K4: H3 = LN3(cat(H2, pooled) @ F2W1 + f2b1) ----
extern "C" __global__ void __launch_bounds__(256, 4)
k_l3(const _Float16* __restrict__ H2, const _Float16* __restrict__ pooledh,
     const _Float16* __restrict__ wt,
     const float* __restrict__ f2b1, const float* __restrict__ f2g1, const float* __restrict__ f2be1,
     _Float16* __restrict__ H3)
{
  __shared__ float2   part[MM * 4];
  __shared__ _Float16 Ph[16 * PSTR];
  __shared__ float    pc[GG * 132];
  const int tid = threadIdx.x, lane = tid & 63, w = tid >> 6;
  const int l15 = lane & 15, lg = lane >> 4, blk = blockIdx.x;

  for (int i = tid; i < GG * HH; i += 256)
    Ph[(i >> 7) * PSTR + (i & 127)] = pooledh[(size_t)(blk * GG) * HH + i];
  for (int i = tid; i < 8 * PSTR; i += 256) Ph[(8) * PSTR + i % (8 * PSTR)] = (_Float16)0.f;
  __syncthreads();

  // pooled-GEMM: pc = f2b1 + pooled @ F2W1[128:256] (wave-local columns)
  {
    const int c0 = 32 * w + l15, c1 = c0 + 16;
    f32x4 accp[2];
    accp[0] = splat4(f2b1[c0]);
    accp[1] = splat4(f2b1[c1]);
    gemm16<4, 128>(Ph, PSTR, wt + 36864, accp, l15, lg, 2 * w);
    if (lg < 2) {
#pragma unroll
      for (int j = 0; j < 4; j++) {
        const int p = lg * 4 + j;
        pc[p * 132 + c0] = accp[0][j];
        pc[p * 132 + c1] = accp[1][j];
      }
    }
  }
  // pc written & read by the same wave's columns -> wave-internal LDS order (R5-proven)

  f32x4 acc[MT][2];
  {
    const int c0 = 32 * w + l15, c1 = c0 + 16;
#pragma unroll
    for (int mt = 0; mt < MT; mt++)
#pragma unroll
      for (int j = 0; j < 4; j++) {
        const int row = mt * 16 + lg * 4 + j;
        const unsigned p = (unsigned)row / 20u;
        acc[mt][0][j] = pc[p * 132 + c0];
        acc[mt][1][j] = pc[p * 132 + c1];
      }
  }
  gemm_g<4, 128, false>(H2 + (size_t)blk * MM * HH, wt + 20480, acc, l15, lg, w);
  ln_partials<false>(acc, nullptr, part, l15, lg, w);
  __syncthreads();
  ln_norm_g<false, false, true>(acc, f2g1, f2be1, nullptr, nullptr,
                                H3 + (size_t)blk * MM * HH, part, l15, lg, w);
}

// ---- K5: pooled2 = max_P(LN4(H3 @ F2W2 + f2b2) * mask); vld ----
extern "C" __global__ void __launch_bounds__(256, 4)
k_l4(const _Float16* __restrict__ H3, const int* __restrict__ maskp,
     const _Float16* __restrict__ wt,
     const float* __restrict__ f2b2, const float* __restrict__ f2g2, const float* __restrict__ f2be2,
     _Float16* __restrict__ pooled2h, float* __restrict__ vldw)
{
  __shared__ float2 part[MM * 4];
  __shared__ int    pmaxI[GG * HH];
  __shared__ float  mf[MM];
  const int tid = threadIdx.x, lane = tid & 63, w = tid >> 6;
  const int l15 = lane & 15, lg = lane >> 4, blk = blockIdx.x;

  const int* mp = maskp + (size_t)blk * MM;
  for (int i = tid; i < MM; i += 256) mf[i] = mp[i] ? 1.f : 0.f;
  for (int i = tid; i < GG * HH; i += 256) pmaxI[i] = 0;

  f32x4 acc[MT][2];
  gemm_g<4, 128, true>(H3 + (size_t)blk * MM * HH, wt + 53248, acc, l15, lg, w);
  ln_partials<true>(acc, f2b2, part, l15, lg, w);
  __syncthreads();
  ln_norm_g<true, true, false>(acc, f2g2, f2be2, mf, pmaxI, nullptr, part, l15, lg, w);
  __syncthreads();
  for (int i = tid; i < GG * HH; i += 256)
    pooled2h[(size_t)(blk * GG) * HH + i] = (_Float16)__int_as_float(pmaxI[i]);
  if (tid < GG) {
    float s = 0.f;
    for (int i = 0; i < PP; i++) s += mf[tid * PP + i];
    vldw[blk * GG + tid] = (s > 0.f) ? 1.f : 0.f;
  }
}

// ---- K6: out = (relu(pooled2 @ FOW1 + fob1) @ FOW2 + fob2) * vld ----
// 64 rows per block, 4 waves (R5-head-proven structure; A direct from global).
extern "C" __global__ void __launch_bounds__(256, 2)
k_head(const _Float16* __restrict__ pooled2h, const float* __restrict__ vldw,
       const _Float16* __restrict__ wt,
       const float* __restrict__ fob1, const float* __restrict__ fob2,
       float* __restrict__ out)
{
  __shared__ _Float16 Z1[64 * PSTR];
  const int tid = threadIdx.x, lane = tid & 63, w = tid >> 6;
  const int l15 = lane & 15, lg = lane >> 4;
  const int rbase = blockIdx.x * 64;

  const _Float16* FOW1t = wt + 69632;
  const _Float16* FOW2t = wt + 86016;

  // z = relu(pooled2 @ FOW1 + fob1): wave w owns cols 32w..32w+31
  {
    f32x4 az[4][2];
    const float bz0 = fob1[32 * w + l15];
    const float bz1 = fob1[32 * w + 16 + l15];
#pragma unroll
    for (int mt = 0; mt < 4; mt++) { az[mt][0] = splat4(bz0); az[mt][1] = splat4(bz1); }
    f16x8 bfr[2][4];
#pragma unroll
    for (int nt = 0; nt < 2; nt++) {
      const _Float16* bp = FOW1t + (size_t)((2 * w + nt) * 16 + l15) * 128 + 4 * lg;
#pragma unroll
      for (int ks = 0; ks < 4; ks++) bfr[nt][ks] = ldfrag(bp + 32 * ks);
    }
#pragma unroll
    for (int mt = 0; mt < 4; mt++) {
      const _Float16* ap = pooled2h + (size_t)(rbase + mt * 16 + l15) * HH + 4 * lg;
#pragma unroll
      for (int ks = 0; ks < 4; ks++) {
        f16x8 a = ldfrag(ap + 32 * ks);
        az[mt][0] = MFMA(a, bfr[0][ks], az[mt][0]);
        az[mt][1] = MFMA(a, bfr[1][ks], az[mt][1]);
      }
    }
#pragma unroll
    for (int mt = 0; mt < 4; mt++)
#pragma unroll
      for (int j = 0; j < 4; j++) {
        const int row = mt * 16 + lg * 4 + j;
        Z1[row * PSTR + 32 * w + l15]      = (_Float16)fmaxf(az[mt][0][j], 0.f);
        Z1[row * PSTR + 32 * w + 16 + l15] = (_Float16)fmaxf(az[mt][1][j], 0.f);
      }
  }
  __syncthreads();

  // out = (z @ FOW2 + fob2) * vld: wave w owns cols 64w..64w+63
  {
    f16x8 a[4][4];
#pragma unroll
    for (int mt = 0; mt < 4; mt++)
#pragma unroll
      for (int ks = 0; ks < 4; ks++)
        a[mt][ks] = ldfrag(Z1 + (mt * 16 + l15) * PSTR + 4 * lg + 32 * ks);
    f32x4 o[4][4];
#pragma unroll
    for (int nt = 0; nt < 4; nt++) {
      const int c = (4 * w + nt) * 16 + l15;
      const float bo = fob2[c];
#pragma unroll
      for (int mt = 0; mt < 4; mt++) o[mt][nt] = splat4(bo);
      const _Float16* bp = FOW2t + (size_t)((4 * w + nt) * 16 + l15) * 128 + 4 * lg;
#pragma unroll
      for (int ks = 0; ks < 4; ks++) {
        f16x8 b = ldfrag(bp + 32 * ks);
#pragma unroll
        for (int mt = 0; mt < 4; mt++) o[mt][nt] = MFMA(a[mt][ks], b, o[mt][nt]);
      }
    }
#pragma unroll
    for (int mt = 0; mt < 4; mt++)
#pragma unroll
      for (int j = 0; j < 4; j++) {
        const int row = mt * 16 + lg * 4 + j;
        const float v = vldw[rbase + row];
#pragma unroll
        for (int nt = 0; nt < 4; nt++)
          out[(size_t)(rbase + row) * OO + (4 * w + nt) * 16 + l15] = o[mt][nt][j] * v;
      }
  }
}

// ================= fallback: R1 fp32 fused kernel (proven, no ws) =============
#define FHP 132
__device__ __forceinline__ void fb_ln_stats(const float* __restrict__ h,
                                            float* __restrict__ stats, int tid)
{
  if (tid < 2 * PP) {
    const int r = tid % PP, half = tid / PP;
    const float4* hp = reinterpret_cast<const float4*>(h + r * FHP + half * 64);
    float s = 0.f, q = 0.f;
#pragma unroll
    for (int i = 0; i < 16; i++) {
      const float4 v = hp[i];
      s += (v.x + v.y) + (v.z + v.w);
      q += (v.x * v.x + v.y * v.y) + (v.z * v.z + v.w * v.w);
    }
    const float s2 = __shfl(s, tid + PP, 64);
    const float q2 = __shfl(q, tid + PP, 64);
    if (half == 0) {
      const float mu  = (s + s2) * (1.0f / HH);
      const float var = (q + q2) * (1.0f / HH) - mu * mu;
      stats[2 * r] = mu;
      stats[2 * r + 1] = 1.0f / sqrtf(var + 1e-5f);
    }
  }
}
__device__ __forceinline__ void fb_mm(const float* __restrict__ hbuf,
                                      const float* __restrict__ W, int c, float acc[PP])
{
  for (int kt = 0; kt < HH / 4; kt++) {
    const float* wp = W + (kt * 4) * HH + c;
    const float w0 = wp[0], w1 = wp[HH], w2 = wp[2 * HH], w3 = wp[3 * HH];
#pragma unroll
    for (int r = 0; r < PP; r++) {
      const float4 v = *reinterpret_cast<const float4*>(hbuf + r * FHP + kt * 4);
      acc[r] = fmaf(v.x, w0, fmaf(v.y, w1, fmaf(v.z, w2, fmaf(v.w, w3, acc[r]))));
    }
  }
}
__device__ __forceinline__ float fb_vdot(const float* __restrict__ vbuf,
                                         const float* __restrict__ W, int ldw, int c)
{
  float s = 0.f;
  for (int kt = 0; kt < HH / 4; kt++) {
    const float4 v = *reinterpret_cast<const float4*>(vbuf + kt * 4);
    const float* wp = W + (kt * 4) * ldw + c;
    s = fmaf(v.x, wp[0], s); s = fmaf(v.y, wp[ldw], s);
    s = fmaf(v.z, wp[2 * ldw], s); s = fmaf(v.w, wp[3 * ldw], s);
  }
  return s;
}
__device__ __forceinline__ void fb_lnblk(float acc[PP], float* __restrict__ hbuf,
                                         float* __restrict__ stats,
                                         const float* __restrict__ G, const float* __restrict__ BE,
                                         const float* __restrict__ mfv, bool domask,
                                         float* __restrict__ pl, int c)
{
  __syncthreads();
#pragma unroll
  for (int r = 0; r < PP; r++) hbuf[r * FHP + c] = acc[r];
  __syncthreads();
  fb_ln_stats(hbuf, stats, c);
  __syncthreads();
  const float gg = G[c], bb = BE[c];
  float pmax = 0.f;
#pragma unroll
  for (int r = 0; r < PP; r++) {
    float v = fmaf((acc[r] - stats[2 * r]) * stats[2 * r + 1], gg, bb);
    v = fmaxf(v, 0.f);
    if (domask) v *= mfv[r];
    acc[r] = v;
    hbuf[r * FHP + c] = v;
    pmax = fmaxf(pmax, v);
  }
  if (domask) pl[c] = pmax;
  __syncthreads();
}
extern "C" __global__ void __launch_bounds__(128, 4)
polyline_fused(const float* __restrict__ poly, const int* __restrict__ mask,
               const float* __restrict__ W1, const float* __restrict__ b1,
               const float* __restrict__ g1, const float* __restrict__ be1,
               const float* __restrict__ W2, const float* __restrict__ b2,
               const float* __restrict__ g2, const float* __restrict__ be2,
               const float* __restrict__ f2W1, const float* __restrict__ f2b1,
               const float* __restrict__ f2g1, const float* __restrict__ f2be1,
               const float* __restrict__ f2W2, const float* __restrict__ f2b2,
               const float* __restrict__ f2g2, const float* __restrict__ f2be2,
               const float* __restrict__ foW1, const float* __restrict__ fob1,
               const float* __restrict__ foW2, const float* __restrict__ fob2,
               float* __restrict__ out)
{
  __shared__ float xs[PP * 13];
  __shared__ float mfv[PP];
  __shared__ float hbuf[PP * FHP];
  __shared__ float stats[PP * 2];
  __shared__ float pl[HH];
  const int bn = blockIdx.x, c = threadIdx.x;
  const float* xp = poly + (size_t)bn * (PP * 13);
  for (int i = c; i < PP * 13; i += 128) xs[i] = xp[i];
  if (c < PP) mfv[c] = (mask[(size_t)bn * PP + c] != 0) ? 1.0f : 0.0f;
  __syncthreads();
  float validf = 0.f;
#pragma unroll
  for (int r = 0; r < PP; r++) validf += mfv[r];
  validf = (validf > 0.f) ? 1.f : 0.f;
  float acc[PP];
  { const float bb = b1[c];
#pragma unroll
    for (int r = 0; r < PP; r++) acc[r] = bb;
    for (int k = 0; k < 13; k++) {
      const float wv = W1[k * HH + c];
#pragma unroll
      for (int r = 0; r < PP; r++) acc[r] = fmaf(xs[r * 13 + k], wv, acc[r]);
    } }
  fb_lnblk(acc, hbuf, stats, g1, be1, mfv, false, pl, c);
  { const float bb = b2[c];
#pragma unroll
    for (int r = 0; r < PP; r++) acc[r] = bb;
    fb_mm(hbuf, W2, c, acc); }
  fb_lnblk(acc, hbuf, stats, g2, be2, mfv, true, pl, c);
  { const float pcv = fb_vdot(pl, f2W1 + HH * HH, HH, c);
    const float bb = f2b1[c] + pcv;
#pragma unroll
    for (int r = 0; r < PP; r++) acc[r] = bb;
    fb_mm(hbuf, f2W1, c, acc); }
  fb_lnblk(acc, hbuf, stats, f2g1, f2be1, mfv, false, pl, c);
  { const float bb = f2b2[c];
#pragma unroll
    for (int r = 0; r < PP; r++) acc[r] = bb;
    fb_mm(hbuf, f2W2, c, acc); }
  fb_lnblk(acc, hbuf, stats, f2g2, f2be2, mfv, true, pl, c);
  { float z = fob1[c] + fb_vdot(pl, foW1, HH, c);
    hbuf[c] = fmaxf(z, 0.f); }
  __syncthreads();
  { float o0 = fob2[c], o1 = fob2[c + HH];
    for (int kt = 0; kt < HH / 4; kt++) {
      const float4 v = *reinterpret_cast<const float4*>(hbuf + kt * 4);
      const float* wp = foW2 + (kt * 4) * OO + c;
      o0 = fmaf(v.x, wp[0], o0); o0 = fmaf(v.y, wp[OO], o0);
      o0 = fmaf(v.z, wp[2 * OO], o0); o0 = fmaf(v.w, wp[3 * OO], o0);
      const float* wq = wp + HH;
      o1 = fmaf(v.x, wq[0], o1); o1 = fmaf(v.y, wq[OO], o1);
      o1 = fmaf(v.z, wq[2 * OO], o1); o1 = fmaf(v.w, wq[3 * OO], o1);
    }
    float* op = out + (size_t)bn * OO;
    op[c] = o0 * validf;
    op[c + HH] = o1 * validf; }
}

// ================================ launch ======================================
extern "C" void kernel_launch(void* const* d_in, const int* in_sizes, int n_in,
                              void* d_out, int out_size, void* d_ws, size_t ws_size,
                              hipStream_t stream)
{
  const float* poly  = (const float*)d_in[0];
  const int*   mask  = (const int*)d_in[1];
  const float* W1    = (const float*)d_in[2];
  const float* b1    = (const float*)d_in[3];
  const float* g1    = (const float*)d_in[4];
  const float* be1   = (const float*)d_in[5];
  const float* W2    = (const float*)d_in[6];
  const float* b2    = (const float*)d_in[7];
  const float* g2    = (const float*)d_in[8];
  const float* be2   = (const float*)d_in[9];
  const float* f2W1  = (const float*)d_in[10];
  const float* f2b1  = (const float*)d_in[11];
  const float* f2g1  = (const float*)d_in[12];
  const float* f2be1 = (const float*)d_in[13];
  const float* f2W2  = (const float*)d_in[14];
  const float* f2b2  = (const float*)d_in[15];
  const float* f2g2  = (const float*)d_in[16];
  const float* f2be2 = (const float*)d_in[17];
  const float* foW1  = (const float*)d_in[18];
  const float* fob1  = (const float*)d_in[19];
  const float* foW2  = (const float*)d_in[20];
  const float* fob2  = (const float*)d_in[21];
  float* out = (float*)d_out;

  const int npoly = in_sizes[0] / (PP * 13);     // 16384
  const int nblk  = npoly / GG;                  // 2048

  // ws layout (bytes)
  const size_t OFF_WT  = 0;                      // 118784 halves = 237,568 B
  const size_t OFF_HA  = 237568;                 // 327680*128 fp16 = 83,886,080
  const size_t OFF_HB  = OFF_HA + 83886080;      // 83,886,080
  const size_t OFF_PL  = OFF_HB + 83886080;      // pooled fp16: 4,194,304
  const size_t OFF_P2  = OFF_PL + 4194304;       // pooled2 fp16: 4,194,304
  const size_t OFF_VL  = OFF_P2 + 4194304;       // vld f32: 65,536
  const size_t NEED    = OFF_VL + 65536;         // ~168.3 MB

  if (ws_size < NEED) {
    // fallback: proven fp32 fused kernel (no workspace)
    polyline_fused<<<dim3(npoly), dim3(128), 0, stream>>>(
        poly, mask, W1, b1, g1, be1, W2, b2, g2, be2,
        f2W1, f2b1, f2g1, f2be1, f2W2, f2b2, f2g2, f2be2,
        foW1, fob1, foW2, fob2, out);
    return;
  }

  char* ws = (char*)d_ws;
  _Float16* wt  = (_Float16*)(ws + OFF_WT);
  _Float16* HA  = (_Float16*)(ws + OFF_HA);
  _Float16* HB  = (_Float16*)(ws + OFF_HB);
  _Float16* PL  = (_Float16*)(ws + OFF_PL);
  _Float16* P2  = (_Float16*)(ws + OFF_P2);
  float*    VL  = (float*)(ws + OFF_VL);

  prep_weights<<<dim3((118784 + 255) / 256), dim3(256), 0, stream>>>(
      W1, W2, f2W1, f2W2, foW1, foW2, wt);

  k_l1<<<dim3(nblk), dim3(256), 0, stream>>>(poly, wt, b1, g1, be1, HA);
  k_l2<<<dim3(nblk), dim3(256), 0, stream>>>(HA, mask, wt, b2, g2, be2, HB, PL);
  k_l3<<<dim3(nblk), dim3(256), 0, stream>>>(HB, PL, wt, f2b1, f2g1, f2be1, HA);
  k_l4<<<dim3(nblk), dim3(256), 0, stream>>>(HA, mask, wt, f2b2, f2g2, f2be2, P2, VL);
  k_head<<<dim3(npoly / 64), dim3(256), 0, stream>>>(P2, VL, wt, fob1, fob2, out);
}

// Round 7
// 286.721 us; speedup vs baseline: 2.2672x; 1.8617x over previous
//
#include <hip/hip_runtime.h>
#include <math.h>

// PolylineNet v7: fully-fused, wave-autonomous, swapped-GEMM fragment pipeline.
// One wave = one polyline (M=32 rows: 20 points + 12 pad), whole net per wave:
//   D = mfma(A=W^T-frag, B=H^T-frag)  ->  lane holds C[m=l15][n=16nt+4lg+j]
//   -> next layer's B-frag = in-register pack (acc[2ks],acc[2ks+1]) -> f16x8
//   LN over channels: 32 in-reg adds + shfl_xor(16,32). Pool: shfl_xor(1,2,4,8)
//   over l15; pooled vector is uniform over l15 == already a valid B-frag.
// Weights pre-swizzled FRAGMENT-LINEAR: frag(f) = 64 lanes x 16B contiguous ->
// every weight load is one coalesced dwordx4 (1KB/wave). No barriers, no LDS
// activations, no intermediate global tensors. Head (fc_out) fused in-wave.

#define PP 20
#define HH 128
#define OO 256
#define NW 4

typedef _Float16 f16x8 __attribute__((ext_vector_type(8)));
typedef float    f32x4 __attribute__((ext_vector_type(4)));

__device__ __forceinline__ f32x4 splat4(float x) { f32x4 v = {x, x, x, x}; return v; }

__device__ __forceinline__ f32x4 MFMA(f16x8 a, f16x8 b, f32x4 c)
{
  return __builtin_amdgcn_mfma_f32_16x16x32_f16(a, b, c, 0, 0, 0);
}

// Pack two f32x4 channel groups (nt=2ks and nt=2ks+1) into one B-operand f16x8:
// halves 0..3 = k = 32ks+4lg+j, halves 4..7 = k = 32ks+16+4lg+j.
__device__ __forceinline__ f16x8 pack8(const f32x4 a, const f32x4 b)
{
  f16x8 h;
  h[0] = (_Float16)a[0]; h[1] = (_Float16)a[1]; h[2] = (_Float16)a[2]; h[3] = (_Float16)a[3];
  h[4] = (_Float16)b[0]; h[5] = (_Float16)b[1]; h[6] = (_Float16)b[2]; h[7] = (_Float16)b[3];
  return h;
}

// One K-step of the swapped GEMM over all 8 N-tiles, both M-tiles.
template<int KSROW>
__device__ __forceinline__ void gemm_ks(const _Float16* __restrict__ wbase, int ks,
                                        const f16x8 bf0, const f16x8 bf1,
                                        f32x4 acc[8][2], int lane)
{
#pragma unroll
  for (int nt = 0; nt < 8; nt++) {
    const f16x8 wf = *(const f16x8*)(wbase + (size_t)(nt * KSROW + ks) * 512 + lane * 8);
    acc[nt][0] = MFMA(wf, bf0, acc[nt][0]);
    acc[nt][1] = MFMA(wf, bf1, acc[nt][1]);
  }
}

__device__ __forceinline__ void zero_acc(f32x4 acc[8][2])
{
#pragma unroll
  for (int nt = 0; nt < 8; nt++) { acc[nt][0] = splat4(0.f); acc[nt][1] = splat4(0.f); }
}

// LayerNorm over channels (n) for both M-tiles; bias add, gamma/beta, ReLU,
// optional (mask * v) + running per-channel max into pm[32].
template<bool DOMASKPOOL>
__device__ __forceinline__ void ln_blk(f32x4 acc[8][2],
                                       const float* __restrict__ bv,
                                       const float* __restrict__ gv,
                                       const float* __restrict__ bev,
                                       float mf0, float mf1,
                                       float* __restrict__ pm, int lg)
{
#pragma unroll
  for (int nt = 0; nt < 8; nt++) {
    const float4 bb = *(const float4*)(bv + 16 * nt + 4 * lg);
    const float bbv[4] = {bb.x, bb.y, bb.z, bb.w};
#pragma unroll
    for (int mt = 0; mt < 2; mt++)
#pragma unroll
      for (int j = 0; j < 4; j++) acc[nt][mt][j] += bbv[j];
  }
  float mu[2], rs[2];
#pragma unroll
  for (int mt = 0; mt < 2; mt++) {
    float s = 0.f, q = 0.f;
#pragma unroll
    for (int nt = 0; nt < 8; nt++)
#pragma unroll
      for (int j = 0; j < 4; j++) { const float v = acc[nt][mt][j]; s += v; q = fmaf(v, v, q); }
    s += __shfl_xor(s, 16, 64); s += __shfl_xor(s, 32, 64);
    q += __shfl_xor(q, 16, 64); q += __shfl_xor(q, 32, 64);
    mu[mt] = s * (1.f / 128.f);
    rs[mt] = rsqrtf(fmaxf(q * (1.f / 128.f) - mu[mt] * mu[mt], 0.f) + 1e-5f);
  }
#pragma unroll
  for (int nt = 0; nt < 8; nt++) {
    const float4 gg4 = *(const float4*)(gv + 16 * nt + 4 * lg);
    const float4 be4 = *(const float4*)(bev + 16 * nt + 4 * lg);
    const float ggv[4] = {gg4.x, gg4.y, gg4.z, gg4.w};
    const float bevv[4] = {be4.x, be4.y, be4.z, be4.w};
#pragma unroll
    for (int mt = 0; mt < 2; mt++) {
      const float m = mt ? mf1 : mf0;
#pragma unroll
      for (int j = 0; j < 4; j++) {
        float v = fmaf((acc[nt][mt][j] - mu[mt]) * rs[mt], ggv[j], bevv[j]);
        v = fmaxf(v, 0.f);
        if (DOMASKPOOL) { v *= m; pm[nt * 4 + j] = fmaxf(pm[nt * 4 + j], v); }
        acc[nt][mt][j] = v;
      }
    }
  }
}

// ---- prep: weights -> fp16 FRAGMENT-LINEAR layout in d_ws ----
// frag f = 512 halves = [64 lanes][8 halves]; lane l: n = nt*16 + (l&15),
// k = ks*32 + 4*(l>>4) + (jj&3) + (jj>=4 ? 16 : 0); value = W[k][n].
// Regions (frag id): L1 0-7 (KS=1) | L2 8-39 (KS=4) | L3 40-103 (KS=8)
//                  | L4 104-135 | H1 136-167 | H2 168-231 (16 nt x KS=4).
__global__ void prep_weights(const float* __restrict__ W1, const float* __restrict__ W2,
                             const float* __restrict__ F2W1, const float* __restrict__ F2W2,
                             const float* __restrict__ FO1, const float* __restrict__ FO2,
                             _Float16* __restrict__ wt)
{
  const int idx = blockIdx.x * 256 + threadIdx.x;
  if (idx >= 118784) return;
  const int jj = idx & 7;
  const int lane = (idx >> 3) & 63;
  const int fg = idx >> 9;
  const int l15 = lane & 15, lg = lane >> 4;
  const int kin = 4 * lg + (jj & 3) + ((jj & 4) << 2);   // +16 for jj>=4
  float v;
  if (fg < 8)        { const int n = fg * 16 + l15;                  v = (kin < 13) ? W1[kin * 128 + n] : 0.f; }
  else if (fg < 40)  { const int f = fg - 8;   const int n = (f >> 2) * 16 + l15, k = (f & 3) * 32 + kin; v = W2[k * 128 + n]; }
  else if (fg < 104) { const int f = fg - 40;  const int n = (f >> 3) * 16 + l15, k = (f & 7) * 32 + kin; v = F2W1[k * 128 + n]; }
  else if (fg < 136) { const int f = fg - 104; const int n = (f >> 2) * 16 + l15, k = (f & 3) * 32 + kin; v = F2W2[k * 128 + n]; }
  else if (fg < 168) { const int f = fg - 136; const int n = (f >> 2) * 16 + l15, k = (f & 3) * 32 + kin; v = FO1[k * 128 + n]; }
  else               { const int f = fg - 168; const int n = (f >> 2) * 16 + l15, k = (f & 3) * 32 + kin; v = FO2[k * 256 + n]; }
  wt[idx] = (_Float16)v;
}

// ---- main fused kernel ----
extern "C" __global__ void __launch_bounds__(256, 3)
polynet_fused(const float* __restrict__ poly, const int* __restrict__ maskp,
              const float* __restrict__ b1,  const float* __restrict__ g1,  const float* __restrict__ be1,
              const float* __restrict__ b2,  const float* __restrict__ g2,  const float* __restrict__ be2,
              const float* __restrict__ f2b1, const float* __restrict__ f2g1, const float* __restrict__ f2be1,
              const float* __restrict__ f2b2, const float* __restrict__ f2g2, const float* __restrict__ f2be2,
              const float* __restrict__ fob1, const float* __restrict__ fob2,
              const _Float16* __restrict__ wt, float* __restrict__ out)
{
  __shared__ float ldsout[NW][OO];

  const int tid  = threadIdx.x;
  const int lane = tid & 63;
  const int w    = tid >> 6;
  const int l15  = lane & 15;
  const int lg   = lane >> 4;
  const int pid  = blockIdx.x * NW + w;

  const _Float16* wtL1 = wt;
  const _Float16* wtL2 = wt + 4096;
  const _Float16* wtL3 = wt + 20480;
  const _Float16* wtL4 = wt + 53248;
  const _Float16* wtH1 = wt + 69632;
  const _Float16* wtH2 = wt + 86016;

  // ---- mask (in-wave) ----
  int mrow = 0;
  if (lane < PP) mrow = maskp[(size_t)pid * PP + lane];
  const float vld = (__ballot(mrow != 0) != 0ULL) ? 1.f : 0.f;
  const int mi0 = __shfl(mrow, l15, 64);
  const int mi1 = __shfl(mrow, 16 + l15, 64);
  const float mf0 = (mi0 != 0) ? 1.f : 0.f;
  const float mf1 = (l15 < 4 && mi1 != 0) ? 1.f : 0.f;

  // ---- X -> B-frags (K=32: 13 real, rest 0). mt0 = points 0..15, mt1 = 16..19 ----
  const float* xp = poly + (size_t)pid * (PP * 13);
  f16x8 x0, x1;
#pragma unroll
  for (int jj = 0; jj < 4; jj++) {
    const int k = 4 * lg + jj;
    const float v0 = (k < 13) ? xp[l15 * 13 + k] : 0.f;
    const float v1 = (k < 13 && l15 < 4) ? xp[(16 + l15) * 13 + k] : 0.f;
    x0[jj] = (_Float16)v0;  x0[4 + jj] = (_Float16)0.f;
    x1[jj] = (_Float16)v1;  x1[4 + jj] = (_Float16)0.f;
  }

  f32x4 acc[8][2];
  f16x8 Hf0[4], Hf1[4];
  float pm[32];

  // ---- L1: K=32 ----
  zero_acc(acc);
  gemm_ks<1>(wtL1, 0, x0, x1, acc, lane);
  ln_blk<false>(acc, b1, g1, be1, mf0, mf1, nullptr, lg);
#pragma unroll
  for (int ks = 0; ks < 4; ks++) {
    Hf0[ks] = pack8(acc[2 * ks][0], acc[2 * ks + 1][0]);
    Hf1[ks] = pack8(acc[2 * ks][1], acc[2 * ks + 1][1]);
  }

  // ---- L2: K=128, mask+pool ----
  zero_acc(acc);
#pragma unroll
  for (int ks = 0; ks < 4; ks++) gemm_ks<4>(wtL2, ks, Hf0[ks], Hf1[ks], acc, lane);
#pragma unroll
  for (int i = 0; i < 32; i++) pm[i] = 0.f;
  ln_blk<true>(acc, b2, g2, be2, mf0, mf1, pm, lg);
#pragma unroll
  for (int i = 0; i < 32; i++) {
    pm[i] = fmaxf(pm[i], __shfl_xor(pm[i], 1, 64));
    pm[i] = fmaxf(pm[i], __shfl_xor(pm[i], 2, 64));
    pm[i] = fmaxf(pm[i], __shfl_xor(pm[i], 4, 64));
    pm[i] = fmaxf(pm[i], __shfl_xor(pm[i], 8, 64));
  }
  f16x8 Pf[4];
#pragma unroll
  for (int ks = 0; ks < 4; ks++) {
    const f32x4 a = {pm[8 * ks + 0], pm[8 * ks + 1], pm[8 * ks + 2], pm[8 * ks + 3]};
    const f32x4 b = {pm[8 * ks + 4], pm[8 * ks + 5], pm[8 * ks + 6], pm[8 * ks + 7]};
    Pf[ks] = pack8(a, b);
  }
  // masked feat -> B-frags for L3
#pragma unroll
  for (int ks = 0; ks < 4; ks++) {
    Hf0[ks] = pack8(acc[2 * ks][0], acc[2 * ks + 1][0]);
    Hf1[ks] = pack8(acc[2 * ks][1], acc[2 * ks + 1][1]);
  }

  // ---- L3: K=256 = feat (ks 0..3) + pooled (ks 4..7, uniform over m) ----
  zero_acc(acc);
#pragma unroll
  for (int ks = 0; ks < 4; ks++) gemm_ks<8>(wtL3, ks, Hf0[ks], Hf1[ks], acc, lane);
#pragma unroll
  for (int ks = 4; ks < 8; ks++) gemm_ks<8>(wtL3, ks, Pf[ks - 4], Pf[ks - 4], acc, lane);
  ln_blk<false>(acc, f2b1, f2g1, f2be1, mf0, mf1, nullptr, lg);
#pragma unroll
  for (int ks = 0; ks < 4; ks++) {
    Hf0[ks] = pack8(acc[2 * ks][0], acc[2 * ks + 1][0]);
    Hf1[ks] = pack8(acc[2 * ks][1], acc[2 * ks + 1][1]);
  }

  // ---- L4: K=128, mask+pool -> pooled2 ----
  zero_acc(acc);
#pragma unroll
  for (int ks = 0; ks < 4; ks++) gemm_ks<4>(wtL4, ks, Hf0[ks], Hf1[ks], acc, lane);
#pragma unroll
  for (int i = 0; i < 32; i++) pm[i] = 0.f;
  ln_blk<true>(acc, f2b2, f2g2, f2be2, mf0, mf1, pm, lg);
#pragma unroll
  for (int i = 0; i < 32; i++) {
    pm[i] = fmaxf(pm[i], __shfl_xor(pm[i], 1, 64));
    pm[i] = fmaxf(pm[i], __shfl_xor(pm[i], 2, 64));
    pm[i] = fmaxf(pm[i], __shfl_xor(pm[i], 4, 64));
    pm[i] = fmaxf(pm[i], __shfl_xor(pm[i], 8, 64));
  }
  f16x8 Pf2[4];
#pragma unroll
  for (int ks = 0; ks < 4; ks++) {
    const f32x4 a = {pm[8 * ks + 0], pm[8 * ks + 1], pm[8 * ks + 2], pm[8 * ks + 3]};
    const f32x4 b = {pm[8 * ks + 4], pm[8 * ks + 5], pm[8 * ks + 6], pm[8 * ks + 7]};
    Pf2[ks] = pack8(a, b);
  }

  // ---- head l1: z = relu(pooled2 @ FOW1 + fob1)  (B uniform over m) ----
  f32x4 ah[8];
#pragma unroll
  for (int nt = 0; nt < 8; nt++) ah[nt] = splat4(0.f);
#pragma unroll
  for (int ks = 0; ks < 4; ks++) {
#pragma unroll
    for (int nt = 0; nt < 8; nt++) {
      const f16x8 wf = *(const f16x8*)(wtH1 + (size_t)(nt * 4 + ks) * 512 + lane * 8);
      ah[nt] = MFMA(wf, Pf2[ks], ah[nt]);
    }
  }
#pragma unroll
  for (int nt = 0; nt < 8; nt++) {
    const float4 bo = *(const float4*)(fob1 + 16 * nt + 4 * lg);
    const float bov[4] = {bo.x, bo.y, bo.z, bo.w};
#pragma unroll
    for (int j = 0; j < 4; j++) ah[nt][j] = fmaxf(ah[nt][j] + bov[j], 0.f);
  }
  f16x8 Zf[4];
#pragma unroll
  for (int ks = 0; ks < 4; ks++) Zf[ks] = pack8(ah[2 * ks], ah[2 * ks + 1]);

  // ---- head l2: out = (z @ FOW2 + fob2) * valid  (16 N-tiles -> acc[nt][mt]) ----
  zero_acc(acc);
#pragma unroll
  for (int ks = 0; ks < 4; ks++) {
#pragma unroll
    for (int nt2 = 0; nt2 < 16; nt2++) {
      const f16x8 wf = *(const f16x8*)(wtH2 + (size_t)(nt2 * 4 + ks) * 512 + lane * 8);
      acc[nt2 & 7][nt2 >> 3] = MFMA(wf, Zf[ks], acc[nt2 & 7][nt2 >> 3]);
    }
  }
#pragma unroll
  for (int nt2 = 0; nt2 < 16; nt2++) {
    const float4 bo = *(const float4*)(fob2 + 16 * nt2 + 4 * lg);
    const float bov[4] = {bo.x, bo.y, bo.z, bo.w};
#pragma unroll
    for (int j = 0; j < 4; j++) {
      const float val = (acc[nt2 & 7][nt2 >> 3][j] + bov[j]) * vld;
      if (l15 == 0) ldsout[w][16 * nt2 + 4 * lg + j] = val;
    }
  }
  // coalesced store (same-wave LDS dependency; no barrier needed)
  const float4 o4 = *(const float4*)(&ldsout[w][lane * 4]);
  *(float4*)(out + (size_t)pid * OO + lane * 4) = o4;
}

extern "C" void kernel_launch(void* const* d_in, const int* in_sizes, int n_in,
                              void* d_out, int out_size, void* d_ws, size_t ws_size,
                              hipStream_t stream)
{
  const float* poly  = (const float*)d_in[0];
  const int*   mask  = (const int*)d_in[1];
  const float* W1    = (const float*)d_in[2];
  const float* b1    = (const float*)d_in[3];
  const float* g1    = (const float*)d_in[4];
  const float* be1   = (const float*)d_in[5];
  const float* W2    = (const float*)d_in[6];
  const float* b2    = (const float*)d_in[7];
  const float* g2    = (const float*)d_in[8];
  const float* be2   = (const float*)d_in[9];
  const float* f2W1  = (const float*)d_in[10];
  const float* f2b1  = (const float*)d_in[11];
  const float* f2g1  = (const float*)d_in[12];
  const float* f2be1 = (const float*)d_in[13];
  const float* f2W2  = (const float*)d_in[14];
  const float* f2b2  = (const float*)d_in[15];
  const float* f2g2  = (const float*)d_in[16];
  const float* f2be2 = (const float*)d_in[17];
  const float* foW1  = (const float*)d_in[18];
  const float* fob1  = (const float*)d_in[19];
  const float* foW2  = (const float*)d_in[20];
  const float* fob2  = (const float*)d_in[21];
  float* out = (float*)d_out;

  _Float16* wt = (_Float16*)d_ws;   // 118784 halves = 237,568 B

  prep_weights<<<dim3((118784 + 255) / 256), dim3(256), 0, stream>>>(
      W1, W2, f2W1, f2W2, foW1, foW2, wt);

  const int npoly = in_sizes[0] / (PP * 13);   // 16384

  polynet_fused<<<dim3(npoly / NW), dim3(256), 0, stream>>>(
      poly, mask, b1, g1, be1, b2, g2, be2,
      f2b1, f2g1, f2be1, f2b2, f2g2, f2be2,
      fob1, fob2, wt, out);
}

// Round 8
// 156.650 us; speedup vs baseline: 4.1498x; 1.8303x over previous
//
#include <hip/hip_runtime.h>
#include <math.h>

// PolylineNet v8: v7's verified swapped-GEMM fragment pipeline + LDS-shared
// weights. Block = 1024 threads = 16 waves = 16 polylines. L1-L4 fragment
// pool (136 KB) staged into LDS once (1 barrier), then waves run autonomously
// (v7 core verbatim, frag reads from LDS). Head fissioned to k_head (R6-proven,
// M=64 tiles); main kernel writes pooled2 (fp16) + valid flags to ws.

#define PP 20
#define HH 128
#define OO 256
#define NW 16          // waves (=polylines) per block
#define PSTR 136       // k_head LDS stride

typedef _Float16 f16x4 __attribute__((ext_vector_type(4)));
typedef _Float16 f16x8 __attribute__((ext_vector_type(8)));
typedef float    f32x4 __attribute__((ext_vector_type(4)));

__device__ __forceinline__ f32x4 splat4(float x) { f32x4 v = {x, x, x, x}; return v; }

__device__ __forceinline__ f32x4 MFMA(f16x8 a, f16x8 b, f32x4 c)
{
  return __builtin_amdgcn_mfma_f32_16x16x32_f16(a, b, c, 0, 0, 0);
}

// R6-style fragment load for k_head ([N][K] row-major weights / dense rows).
__device__ __forceinline__ f16x8 ldfrag2(const _Float16* p)
{
  f16x8 r;
  f16x4* r4 = reinterpret_cast<f16x4*>(&r);
  r4[0] = *reinterpret_cast<const f16x4*>(p);
  r4[1] = *reinterpret_cast<const f16x4*>(p + 16);
  return r;
}

__device__ __forceinline__ f16x8 pack8(const f32x4 a, const f32x4 b)
{
  f16x8 h;
  h[0] = (_Float16)a[0]; h[1] = (_Float16)a[1]; h[2] = (_Float16)a[2]; h[3] = (_Float16)a[3];
  h[4] = (_Float16)b[0]; h[5] = (_Float16)b[1]; h[6] = (_Float16)b[2]; h[7] = (_Float16)b[3];
  return h;
}

// One K-step over all 8 N-tiles, both M-tiles (v7-verified; wbase now LDS).
template<int KSROW>
__device__ __forceinline__ void gemm_ks(const _Float16* wbase, int ks,
                                        const f16x8 bf0, const f16x8 bf1,
                                        f32x4 acc[8][2], int lane)
{
#pragma unroll
  for (int nt = 0; nt < 8; nt++) {
    const f16x8 wf = *(const f16x8*)(wbase + (size_t)(nt * KSROW + ks) * 512 + lane * 8);
    acc[nt][0] = MFMA(wf, bf0, acc[nt][0]);
    acc[nt][1] = MFMA(wf, bf1, acc[nt][1]);
  }
}

__device__ __forceinline__ void zero_acc(f32x4 acc[8][2])
{
#pragma unroll
  for (int nt = 0; nt < 8; nt++) { acc[nt][0] = splat4(0.f); acc[nt][1] = splat4(0.f); }
}

// v7-verified LayerNorm over channels.
template<bool DOMASKPOOL>
__device__ __forceinline__ void ln_blk(f32x4 acc[8][2],
                                       const float* __restrict__ bv,
                                       const float* __restrict__ gv,
                                       const float* __restrict__ bev,
                                       float mf0, float mf1,
                                       float* __restrict__ pm, int lg)
{
#pragma unroll
  for (int nt = 0; nt < 8; nt++) {
    const float4 bb = *(const float4*)(bv + 16 * nt + 4 * lg);
    const float bbv[4] = {bb.x, bb.y, bb.z, bb.w};
#pragma unroll
    for (int mt = 0; mt < 2; mt++)
#pragma unroll
      for (int j = 0; j < 4; j++) acc[nt][mt][j] += bbv[j];
  }
  float mu[2], rs[2];
#pragma unroll
  for (int mt = 0; mt < 2; mt++) {
    float s = 0.f, q = 0.f;
#pragma unroll
    for (int nt = 0; nt < 8; nt++)
#pragma unroll
      for (int j = 0; j < 4; j++) { const float v = acc[nt][mt][j]; s += v; q = fmaf(v, v, q); }
    s += __shfl_xor(s, 16, 64); s += __shfl_xor(s, 32, 64);
    q += __shfl_xor(q, 16, 64); q += __shfl_xor(q, 32, 64);
    mu[mt] = s * (1.f / 128.f);
    rs[mt] = rsqrtf(fmaxf(q * (1.f / 128.f) - mu[mt] * mu[mt], 0.f) + 1e-5f);
  }
#pragma unroll
  for (int nt = 0; nt < 8; nt++) {
    const float4 gg4 = *(const float4*)(gv + 16 * nt + 4 * lg);
    const float4 be4 = *(const float4*)(bev + 16 * nt + 4 * lg);
    const float ggv[4] = {gg4.x, gg4.y, gg4.z, gg4.w};
    const float bevv[4] = {be4.x, be4.y, be4.z, be4.w};
#pragma unroll
    for (int mt = 0; mt < 2; mt++) {
      const float m = mt ? mf1 : mf0;
#pragma unroll
      for (int j = 0; j < 4; j++) {
        float v = fmaf((acc[nt][mt][j] - mu[mt]) * rs[mt], ggv[j], bevv[j]);
        v = fmaxf(v, 0.f);
        if (DOMASKPOOL) { v *= m; pm[nt * 4 + j] = fmaxf(pm[nt * 4 + j], v); }
        acc[nt][mt][j] = v;
      }
    }
  }
}

// ---- prep: L1-L4 fragment-linear (v7-verified) + FOW1/FOW2 [N][K] (R6-verified) ----
__global__ void prep_weights(const float* __restrict__ W1, const float* __restrict__ W2,
                             const float* __restrict__ F2W1, const float* __restrict__ F2W2,
                             const float* __restrict__ FO1, const float* __restrict__ FO2,
                             _Float16* __restrict__ wt)
{
  const int idx = blockIdx.x * 256 + threadIdx.x;
  if (idx >= 118784) return;
  float v;
  if (idx < 69632) {
    // fragment-linear regions: L1 fg 0-7 | L2 8-39 | L3 40-103 | L4 104-135
    const int jj = idx & 7;
    const int lane = (idx >> 3) & 63;
    const int fg = idx >> 9;
    const int l15 = lane & 15, lg = lane >> 4;
    const int kin = 4 * lg + (jj & 3) + ((jj & 4) << 2);
    if (fg < 8)        { const int n = fg * 16 + l15;                  v = (kin < 13) ? W1[kin * 128 + n] : 0.f; }
    else if (fg < 40)  { const int f = fg - 8;   const int n = (f >> 2) * 16 + l15, k = (f & 3) * 32 + kin; v = W2[k * 128 + n]; }
    else if (fg < 104) { const int f = fg - 40;  const int n = (f >> 3) * 16 + l15, k = (f & 7) * 32 + kin; v = F2W1[k * 128 + n]; }
    else               { const int f = fg - 104; const int n = (f >> 2) * 16 + l15, k = (f & 3) * 32 + kin; v = F2W2[k * 128 + n]; }
  } else if (idx < 86016) { const int j = idx - 69632; const int n = j >> 7, k = j & 127; v = FO1[k * 128 + n]; }
  else                    { const int j = idx - 86016; const int n = j >> 7, k = j & 127; v = FO2[k * 256 + n]; }
  wt[idx] = (_Float16)v;
}

// ---- main kernel: 16 waves, LDS-shared weights, 1 barrier ----
extern "C" __global__ void __launch_bounds__(1024, 1)
polynet_main(const float* __restrict__ poly, const int* __restrict__ maskp,
             const float* __restrict__ b1,  const float* __restrict__ g1,  const float* __restrict__ be1,
             const float* __restrict__ b2,  const float* __restrict__ g2,  const float* __restrict__ be2,
             const float* __restrict__ f2b1, const float* __restrict__ f2g1, const float* __restrict__ f2be1,
             const float* __restrict__ f2b2, const float* __restrict__ f2g2, const float* __restrict__ f2be2,
             const _Float16* __restrict__ wt,
             _Float16* __restrict__ pooled2h, float* __restrict__ vldw)
{
  __shared__ _Float16 ldsw[69632];          // L1-L4 fragment pool (136 KB)
  __shared__ _Float16 ldsp[NW][HH];         // pooled2 staging (4 KB)

  const int tid  = threadIdx.x;
  const int lane = tid & 63;
  const int w    = tid >> 6;
  const int l15  = lane & 15;
  const int lg   = lane >> 4;
  const int pid  = blockIdx.x * NW + w;

  // ---- stage weights (coalesced uint4 copy), one barrier ----
  {
    const uint4* src = (const uint4*)wt;
    uint4* dst = (uint4*)ldsw;
    for (int i = tid; i < 8704; i += 1024) dst[i] = src[i];
  }

  // ---- mask (in-wave, v7-verified) ----
  int mrow = 0;
  if (lane < PP) mrow = maskp[(size_t)pid * PP + lane];
  const float vld = (__ballot(mrow != 0) != 0ULL) ? 1.f : 0.f;
  const int mi0 = __shfl(mrow, l15, 64);
  const int mi1 = __shfl(mrow, 16 + l15, 64);
  const float mf0 = (mi0 != 0) ? 1.f : 0.f;
  const float mf1 = (l15 < 4 && mi1 != 0) ? 1.f : 0.f;

  // ---- X -> B-frags (v7-verified) ----
  const float* xp = poly + (size_t)pid * (PP * 13);
  f16x8 x0, x1;
#pragma unroll
  for (int jj = 0; jj < 4; jj++) {
    const int k = 4 * lg + jj;
    const float v0 = (k < 13) ? xp[l15 * 13 + k] : 0.f;
    const float v1 = (k < 13 && l15 < 4) ? xp[(16 + l15) * 13 + k] : 0.f;
    x0[jj] = (_Float16)v0;  x0[4 + jj] = (_Float16)0.f;
    x1[jj] = (_Float16)v1;  x1[4 + jj] = (_Float16)0.f;
  }

  __syncthreads();   // weights staged

  const _Float16* wtL1 = ldsw;
  const _Float16* wtL2 = ldsw + 4096;
  const _Float16* wtL3 = ldsw + 20480;
  const _Float16* wtL4 = ldsw + 53248;

  f32x4 acc[8][2];
  f16x8 Hf0[4], Hf1[4];
  float pm[32];

  // ---- L1: K=32 ----
  zero_acc(acc);
  gemm_ks<1>(wtL1, 0, x0, x1, acc, lane);
  ln_blk<false>(acc, b1, g1, be1, mf0, mf1, nullptr, lg);
#pragma unroll
  for (int ks = 0; ks < 4; ks++) {
    Hf0[ks] = pack8(acc[2 * ks][0], acc[2 * ks + 1][0]);
    Hf1[ks] = pack8(acc[2 * ks][1], acc[2 * ks + 1][1]);
  }

  // ---- L2: K=128, mask+pool ----
  zero_acc(acc);
#pragma unroll
  for (int ks = 0; ks < 4; ks++) gemm_ks<4>(wtL2, ks, Hf0[ks], Hf1[ks], acc, lane);
#pragma unroll
  for (int i = 0; i < 32; i++) pm[i] = 0.f;
  ln_blk<true>(acc, b2, g2, be2, mf0, mf1, pm, lg);
#pragma unroll
  for (int i = 0; i < 32; i++) {
    pm[i] = fmaxf(pm[i], __shfl_xor(pm[i], 1, 64));
    pm[i] = fmaxf(pm[i], __shfl_xor(pm[i], 2, 64));
    pm[i] = fmaxf(pm[i], __shfl_xor(pm[i], 4, 64));
    pm[i] = fmaxf(pm[i], __shfl_xor(pm[i], 8, 64));
  }
  f16x8 Pf[4];
#pragma unroll
  for (int ks = 0; ks < 4; ks++) {
    const f32x4 a = {pm[8 * ks + 0], pm[8 * ks + 1], pm[8 * ks + 2], pm[8 * ks + 3]};
    const f32x4 b = {pm[8 * ks + 4], pm[8 * ks + 5], pm[8 * ks + 6], pm[8 * ks + 7]};
    Pf[ks] = pack8(a, b);
  }
#pragma unroll
  for (int ks = 0; ks < 4; ks++) {
    Hf0[ks] = pack8(acc[2 * ks][0], acc[2 * ks + 1][0]);
    Hf1[ks] = pack8(acc[2 * ks][1], acc[2 * ks + 1][1]);
  }

  // ---- L3: K=256 = feat + pooled ----
  zero_acc(acc);
#pragma unroll
  for (int ks = 0; ks < 4; ks++) gemm_ks<8>(wtL3, ks, Hf0[ks], Hf1[ks], acc, lane);
#pragma unroll
  for (int ks = 4; ks < 8; ks++) gemm_ks<8>(wtL3, ks, Pf[ks - 4], Pf[ks - 4], acc, lane);
  ln_blk<false>(acc, f2b1, f2g1, f2be1, mf0, mf1, nullptr, lg);
#pragma unroll
  for (int ks = 0; ks < 4; ks++) {
    Hf0[ks] = pack8(acc[2 * ks][0], acc[2 * ks + 1][0]);
    Hf1[ks] = pack8(acc[2 * ks][1], acc[2 * ks + 1][1]);
  }

  // ---- L4: K=128, mask+pool -> pooled2 ----
  zero_acc(acc);
#pragma unroll
  for (int ks = 0; ks < 4; ks++) gemm_ks<4>(wtL4, ks, Hf0[ks], Hf1[ks], acc, lane);
#pragma unroll
  for (int i = 0; i < 32; i++) pm[i] = 0.f;
  ln_blk<true>(acc, f2b2, f2g2, f2be2, mf0, mf1, pm, lg);
#pragma unroll
  for (int i = 0; i < 32; i++) {
    pm[i] = fmaxf(pm[i], __shfl_xor(pm[i], 1, 64));
    pm[i] = fmaxf(pm[i], __shfl_xor(pm[i], 2, 64));
    pm[i] = fmaxf(pm[i], __shfl_xor(pm[i], 4, 64));
    pm[i] = fmaxf(pm[i], __shfl_xor(pm[i], 8, 64));
  }

  // ---- emit pooled2 (fp16) + vld; coalesced via per-wave LDS row ----
  if (l15 == 0) {
#pragma unroll
    for (int nt = 0; nt < 8; nt++)
#pragma unroll
      for (int j = 0; j < 4; j++)
        ldsp[w][nt * 16 + 4 * lg + j] = (_Float16)pm[nt * 4 + j];
  }
  // same-wave LDS dependency (v7-verified pattern, no barrier)
  const unsigned int pv = *(const unsigned int*)(&ldsp[w][lane * 2]);
  *(unsigned int*)(pooled2h + (size_t)pid * HH + lane * 2) = pv;
  if (lane == 0) vldw[pid] = vld;
}

// ---- k_head (R6-verified): out = (relu(pooled2 @ FOW1 + fob1) @ FOW2 + fob2) * vld ----
extern "C" __global__ void __launch_bounds__(256, 2)
k_head(const _Float16* __restrict__ pooled2h, const float* __restrict__ vldw,
       const _Float16* __restrict__ wt,
       const float* __restrict__ fob1, const float* __restrict__ fob2,
       float* __restrict__ out)
{
  __shared__ _Float16 Z1[64 * PSTR];
  const int tid = threadIdx.x, lane = tid & 63, w = tid >> 6;
  const int l15 = lane & 15, lg = lane >> 4;
  const int rbase = blockIdx.x * 64;

  const _Float16* FOW1t = wt + 69632;
  const _Float16* FOW2t = wt + 86016;

  {
    f32x4 az[4][2];
    const float bz0 = fob1[32 * w + l15];
    const float bz1 = fob1[32 * w + 16 + l15];
#pragma unroll
    for (int mt = 0; mt < 4; mt++) { az[mt][0] = splat4(bz0); az[mt][1] = splat4(bz1); }
    f16x8 bfr[2][4];
#pragma unroll
    for (int nt = 0; nt < 2; nt++) {
      const _Float16* bp = FOW1t + (size_t)((2 * w + nt) * 16 + l15) * 128 + 4 * lg;
#pragma unroll
      for (int ks = 0; ks < 4; ks++) bfr[nt][ks] = ldfrag2(bp + 32 * ks);
    }
#pragma unroll
    for (int mt = 0; mt < 4; mt++) {
      const _Float16* ap = pooled2h + (size_t)(rbase + mt * 16 + l15) * HH + 4 * lg;
#pragma unroll
      for (int ks = 0; ks < 4; ks++) {
        f16x8 a = ldfrag2(ap + 32 * ks);
        az[mt][0] = MFMA(a, bfr[0][ks], az[mt][0]);
        az[mt][1] = MFMA(a, bfr[1][ks], az[mt][1]);
      }
    }
#pragma unroll
    for (int mt = 0; mt < 4; mt++)
#pragma unroll
      for (int j = 0; j < 4; j++) {
        const int row = mt * 16 + lg * 4 + j;
        Z1[row * PSTR + 32 * w + l15]      = (_Float16)fmaxf(az[mt][0][j], 0.f);
        Z1[row * PSTR + 32 * w + 16 + l15] = (_Float16)fmaxf(az[mt][1][j], 0.f);
      }
  }
  __syncthreads();

  {
    f16x8 a[4][4];
#pragma unroll
    for (int mt = 0; mt < 4; mt++)
#pragma unroll
      for (int ks = 0; ks < 4; ks++)
        a[mt][ks] = ldfrag2(Z1 + (mt * 16 + l15) * PSTR + 4 * lg + 32 * ks);
    f32x4 o[4][4];
#pragma unroll
    for (int nt = 0; nt < 4; nt++) {
      const int c = (4 * w + nt) * 16 + l15;
      const float bo = fob2[c];
#pragma unroll
      for (int mt = 0; mt < 4; mt++) o[mt][nt] = splat4(bo);
      const _Float16* bp = FOW2t + (size_t)((4 * w + nt) * 16 + l15) * 128 + 4 * lg;
#pragma unroll
      for (int ks = 0; ks < 4; ks++) {
        f16x8 b = ldfrag2(bp + 32 * ks);
#pragma unroll
        for (int mt = 0; mt < 4; mt++) o[mt][nt] = MFMA(a[mt][ks], b, o[mt][nt]);
      }
    }
#pragma unroll
    for (int mt = 0; mt < 4; mt++)
#pragma unroll
      for (int j = 0; j < 4; j++) {
        const int row = mt * 16 + lg * 4 + j;
        const float v = vldw[rbase + row];
#pragma unroll
        for (int nt = 0; nt < 4; nt++)
          out[(size_t)(rbase + row) * OO + (4 * w + nt) * 16 + l15] = o[mt][nt][j] * v;
      }
  }
}

extern "C" void kernel_launch(void* const* d_in, const int* in_sizes, int n_in,
                              void* d_out, int out_size, void* d_ws, size_t ws_size,
                              hipStream_t stream)
{
  const float* poly  = (const float*)d_in[0];
  const int*   mask  = (const int*)d_in[1];
  const float* W1    = (const float*)d_in[2];
  const float* b1    = (const float*)d_in[3];
  const float* g1    = (const float*)d_in[4];
  const float* be1   = (const float*)d_in[5];
  const float* W2    = (const float*)d_in[6];
  const float* b2    = (const float*)d_in[7];
  const float* g2    = (const float*)d_in[8];
  const float* be2   = (const float*)d_in[9];
  const float* f2W1  = (const float*)d_in[10];
  const float* f2b1  = (const float*)d_in[11];
  const float* f2g1  = (const float*)d_in[12];
  const float* f2be1 = (const float*)d_in[13];
  const float* f2W2  = (const float*)d_in[14];
  const float* f2b2  = (const float*)d_in[15];
  const float* f2g2  = (const float*)d_in[16];
  const float* f2be2 = (const float*)d_in[17];
  const float* foW1  = (const float*)d_in[18];
  const float* fob1  = (const float*)d_in[19];
  const float* foW2  = (const float*)d_in[20];
  const float* fob2  = (const float*)d_in[21];
  float* out = (float*)d_out;

  const int npoly = in_sizes[0] / (PP * 13);   // 16384

  // ws layout: wt fp16 118784 halves (237,568 B) | pooled2h fp16 npoly*128 | vldw f32 npoly
  char* ws = (char*)d_ws;
  _Float16* wt       = (_Float16*)ws;
  _Float16* pooled2h = (_Float16*)(ws + 237568);
  float*    vldw     = (float*)(ws + 237568 + (size_t)npoly * HH * 2);

  prep_weights<<<dim3((118784 + 255) / 256), dim3(256), 0, stream>>>(
      W1, W2, f2W1, f2W2, foW1, foW2, wt);

  polynet_main<<<dim3(npoly / NW), dim3(1024), 0, stream>>>(
      poly, mask, b1, g1, be1, b2, g2, be2,
      f2b1, f2g1, f2be1, f2b2, f2g2, f2be2,
      wt, pooled2h, vldw);

  k_head<<<dim3(npoly / 64), dim3(256), 0, stream>>>(
      pooled2h, vldw, wt, fob1, fob2, out);
}

// Round 10
// 155.236 us; speedup vs baseline: 4.1876x; 1.0091x over previous
//
#include <hip/hip_runtime.h>
#include <math.h>

// PolylineNet v9b: v8 (verified) + packed-math VALU diet. (v9 with the
// cvt_pkrtz return-type fix: builtin returns __fp16x2, union-reinterpret.)
// - LN elementwise fully vectorized on f32x4 (v_pk_* VOP3P)
// - normalize = 2 fused vector FMAs (fold mu,rs into per-channel affine)
// - f32->f16 packing via v_cvt_pkrtz (1 inst / 2 elems)
// Structure, layout, sync identical to v8 (16 waves/block, LDS weight pool,
// 1 barrier, head fissioned to k_head).

#define PP 20
#define HH 128
#define OO 256
#define NW 16          // waves (=polylines) per block
#define PSTR 136       // k_head LDS stride

typedef __fp16   fp16x2 __attribute__((ext_vector_type(2)));   // cvt_pkrtz return type
typedef _Float16 f16x4 __attribute__((ext_vector_type(4)));
typedef _Float16 f16x8 __attribute__((ext_vector_type(8)));
typedef float    f32x4 __attribute__((ext_vector_type(4)));

__device__ __forceinline__ f32x4 splat4(float x) { f32x4 v = {x, x, x, x}; return v; }

__device__ __forceinline__ f32x4 max4(f32x4 a, f32x4 b)
{
#if __has_builtin(__builtin_elementwise_max)
  return __builtin_elementwise_max(a, b);
#else
  f32x4 r;
  r[0] = fmaxf(a[0], b[0]); r[1] = fmaxf(a[1], b[1]);
  r[2] = fmaxf(a[2], b[2]); r[3] = fmaxf(a[3], b[3]);
  return r;
#endif
}

__device__ __forceinline__ f32x4 MFMA(f16x8 a, f16x8 b, f32x4 c)
{
  return __builtin_amdgcn_mfma_f32_16x16x32_f16(a, b, c, 0, 0, 0);
}

// R6-style fragment load for k_head ([N][K] row-major weights / dense rows).
__device__ __forceinline__ f16x8 ldfrag2(const _Float16* p)
{
  f16x8 r;
  f16x4* r4 = reinterpret_cast<f16x4*>(&r);
  r4[0] = *reinterpret_cast<const f16x4*>(p);
  r4[1] = *reinterpret_cast<const f16x4*>(p + 16);
  return r;
}

// Pack two f32x4 channel groups into one B-operand f16x8 via v_cvt_pkrtz.
__device__ __forceinline__ f16x8 pack8(const f32x4 a, const f32x4 b)
{
  union { fp16x2 h2[4]; f16x8 h8; } u;
  u.h2[0] = __builtin_amdgcn_cvt_pkrtz(a[0], a[1]);
  u.h2[1] = __builtin_amdgcn_cvt_pkrtz(a[2], a[3]);
  u.h2[2] = __builtin_amdgcn_cvt_pkrtz(b[0], b[1]);
  u.h2[3] = __builtin_amdgcn_cvt_pkrtz(b[2], b[3]);
  return u.h8;
}

// One K-step over all 8 N-tiles, both M-tiles (v7/v8-verified; wbase in LDS).
template<int KSROW>
__device__ __forceinline__ void gemm_ks(const _Float16* wbase, int ks,
                                        const f16x8 bf0, const f16x8 bf1,
                                        f32x4 acc[8][2], int lane)
{
#pragma unroll
  for (int nt = 0; nt < 8; nt++) {
    const f16x8 wf = *(const f16x8*)(wbase + (size_t)(nt * KSROW + ks) * 512 + lane * 8);
    acc[nt][0] = MFMA(wf, bf0, acc[nt][0]);
    acc[nt][1] = MFMA(wf, bf1, acc[nt][1]);
  }
}

__device__ __forceinline__ void zero_acc(f32x4 acc[8][2])
{
#pragma unroll
  for (int nt = 0; nt < 8; nt++) { acc[nt][0] = splat4(0.f); acc[nt][1] = splat4(0.f); }
}

// LayerNorm over channels, fully vectorized (semantics identical to v8's ln_blk).
template<bool DOMASKPOOL>
__device__ __forceinline__ void ln_blk(f32x4 acc[8][2],
                                       const float* __restrict__ bv,
                                       const float* __restrict__ gv,
                                       const float* __restrict__ bev,
                                       float mf0, float mf1,
                                       f32x4 pm[8], int lg)
{
  // bias add + moments
  f32x4 sv0 = splat4(0.f), sv1 = splat4(0.f), qv0 = splat4(0.f), qv1 = splat4(0.f);
#pragma unroll
  for (int nt = 0; nt < 8; nt++) {
    const f32x4 bb = *(const f32x4*)(bv + 16 * nt + 4 * lg);
    f32x4 v0 = acc[nt][0] + bb;
    f32x4 v1 = acc[nt][1] + bb;
    acc[nt][0] = v0;  acc[nt][1] = v1;
    sv0 += v0;  qv0 = v0 * v0 + qv0;
    sv1 += v1;  qv1 = v1 * v1 + qv1;
  }
  float mu[2], rs[2];
#pragma unroll
  for (int mt = 0; mt < 2; mt++) {
    const f32x4 sv = mt ? sv1 : sv0;
    const f32x4 qv = mt ? qv1 : qv0;
    float s = (sv[0] + sv[1]) + (sv[2] + sv[3]);
    float q = (qv[0] + qv[1]) + (qv[2] + qv[3]);
    s += __shfl_xor(s, 16, 64); s += __shfl_xor(s, 32, 64);
    q += __shfl_xor(q, 16, 64); q += __shfl_xor(q, 32, 64);
    mu[mt] = s * (1.f / 128.f);
    rs[mt] = rsqrtf(fmaxf(q * (1.f / 128.f) - mu[mt] * mu[mt], 0.f) + 1e-5f);
  }
  // normalize: v = fma(fma(acc, rs, -mu*rs), g, be); relu; mask; pool
  const f32x4 z4 = splat4(0.f);
  const f32x4 rs0 = splat4(rs[0]),           rs1 = splat4(rs[1]);
  const f32x4 nm0 = splat4(-mu[0] * rs[0]),  nm1 = splat4(-mu[1] * rs[1]);
  const f32x4 m0  = splat4(mf0),             m1  = splat4(mf1);
#pragma unroll
  for (int nt = 0; nt < 8; nt++) {
    const f32x4 g4  = *(const f32x4*)(gv  + 16 * nt + 4 * lg);
    const f32x4 be4 = *(const f32x4*)(bev + 16 * nt + 4 * lg);
    f32x4 t0 = acc[nt][0] * rs0 + nm0;
    f32x4 t1 = acc[nt][1] * rs1 + nm1;
    f32x4 v0 = max4(t0 * g4 + be4, z4);
    f32x4 v1 = max4(t1 * g4 + be4, z4);
    if (DOMASKPOOL) {
      v0 = v0 * m0;
      v1 = v1 * m1;
      pm[nt] = max4(pm[nt], max4(v0, v1));
    }
    acc[nt][0] = v0;  acc[nt][1] = v1;
  }
}

// ---- prep: L1-L4 fragment-linear (v7-verified) + FOW1/FOW2 [N][K] (R6-verified) ----
__global__ void prep_weights(const float* __restrict__ W1, const float* __restrict__ W2,
                             const float* __restrict__ F2W1, const float* __restrict__ F2W2,
                             const float* __restrict__ FO1, const float* __restrict__ FO2,
                             _Float16* __restrict__ wt)
{
  const int idx = blockIdx.x * 256 + threadIdx.x;
  if (idx >= 118784) return;
  float v;
  if (idx < 69632) {
    const int jj = idx & 7;
    const int lane = (idx >> 3) & 63;
    const int fg = idx >> 9;
    const int l15 = lane & 15, lg = lane >> 4;
    const int kin = 4 * lg + (jj & 3) + ((jj & 4) << 2);
    if (fg < 8)        { const int n = fg * 16 + l15;                  v = (kin < 13) ? W1[kin * 128 + n] : 0.f; }
    else if (fg < 40)  { const int f = fg - 8;   const int n = (f >> 2) * 16 + l15, k = (f & 3) * 32 + kin; v = W2[k * 128 + n]; }
    else if (fg < 104) { const int f = fg - 40;  const int n = (f >> 3) * 16 + l15, k = (f & 7) * 32 + kin; v = F2W1[k * 128 + n]; }
    else               { const int f = fg - 104; const int n = (f >> 2) * 16 + l15, k = (f & 3) * 32 + kin; v = F2W2[k * 128 + n]; }
  } else if (idx < 86016) { const int j = idx - 69632; const int n = j >> 7, k = j & 127; v = FO1[k * 128 + n]; }
  else                    { const int j = idx - 86016; const int n = j >> 7, k = j & 127; v = FO2[k * 256 + n]; }
  wt[idx] = (_Float16)v;
}

// ---- main kernel: 16 waves, LDS-shared weights, 1 barrier (v8-verified) ----
extern "C" __global__ void __launch_bounds__(1024, 1)
polynet_main(const float* __restrict__ poly, const int* __restrict__ maskp,
             const float* __restrict__ b1,  const float* __restrict__ g1,  const float* __restrict__ be1,
             const float* __restrict__ b2,  const float* __restrict__ g2,  const float* __restrict__ be2,
             const float* __restrict__ f2b1, const float* __restrict__ f2g1, const float* __restrict__ f2be1,
             const float* __restrict__ f2b2, const float* __restrict__ f2g2, const float* __restrict__ f2be2,
             const _Float16* __restrict__ wt,
             _Float16* __restrict__ pooled2h, float* __restrict__ vldw)
{
  __shared__ _Float16 ldsw[69632];          // L1-L4 fragment pool (136 KB)
  __shared__ _Float16 ldsp[NW][HH];         // pooled2 staging (4 KB)

  const int tid  = threadIdx.x;
  const int lane = tid & 63;
  const int w    = tid >> 6;
  const int l15  = lane & 15;
  const int lg   = lane >> 4;
  const int pid  = blockIdx.x * NW + w;

  // ---- stage weights (coalesced uint4 copy), one barrier ----
  {
    const uint4* src = (const uint4*)wt;
    uint4* dst = (uint4*)ldsw;
    for (int i = tid; i < 8704; i += 1024) dst[i] = src[i];
  }

  // ---- mask (in-wave) ----
  int mrow = 0;
  if (lane < PP) mrow = maskp[(size_t)pid * PP + lane];
  const float vld = (__ballot(mrow != 0) != 0ULL) ? 1.f : 0.f;
  const int mi0 = __shfl(mrow, l15, 64);
  const int mi1 = __shfl(mrow, 16 + l15, 64);
  const float mf0 = (mi0 != 0) ? 1.f : 0.f;
  const float mf1 = (l15 < 4 && mi1 != 0) ? 1.f : 0.f;

  // ---- X -> B-frags ----
  const float* xp = poly + (size_t)pid * (PP * 13);
  f16x8 x0, x1;
#pragma unroll
  for (int jj = 0; jj < 4; jj++) {
    const int k = 4 * lg + jj;
    const float v0 = (k < 13) ? xp[l15 * 13 + k] : 0.f;
    const float v1 = (k < 13 && l15 < 4) ? xp[(16 + l15) * 13 + k] : 0.f;
    x0[jj] = (_Float16)v0;  x0[4 + jj] = (_Float16)0.f;
    x1[jj] = (_Float16)v1;  x1[4 + jj] = (_Float16)0.f;
  }

  __syncthreads();   // weights staged

  const _Float16* wtL1 = ldsw;
  const _Float16* wtL2 = ldsw + 4096;
  const _Float16* wtL3 = ldsw + 20480;
  const _Float16* wtL4 = ldsw + 53248;

  f32x4 acc[8][2];
  f16x8 Hf0[4], Hf1[4];
  f32x4 pm[8];

  // ---- L1: K=32 ----
  zero_acc(acc);
  gemm_ks<1>(wtL1, 0, x0, x1, acc, lane);
  ln_blk<false>(acc, b1, g1, be1, mf0, mf1, pm, lg);
#pragma unroll
  for (int ks = 0; ks < 4; ks++) {
    Hf0[ks] = pack8(acc[2 * ks][0], acc[2 * ks + 1][0]);
    Hf1[ks] = pack8(acc[2 * ks][1], acc[2 * ks + 1][1]);
  }

  // ---- L2: K=128, mask+pool ----
  zero_acc(acc);
#pragma unroll
  for (int ks = 0; ks < 4; ks++) gemm_ks<4>(wtL2, ks, Hf0[ks], Hf1[ks], acc, lane);
#pragma unroll
  for (int nt = 0; nt < 8; nt++) pm[nt] = splat4(0.f);
  ln_blk<true>(acc, b2, g2, be2, mf0, mf1, pm, lg);
#pragma unroll
  for (int nt = 0; nt < 8; nt++)
#pragma unroll
    for (int j = 0; j < 4; j++) {
      float p = pm[nt][j];
      p = fmaxf(p, __shfl_xor(p, 1, 64));
      p = fmaxf(p, __shfl_xor(p, 2, 64));
      p = fmaxf(p, __shfl_xor(p, 4, 64));
      p = fmaxf(p, __shfl_xor(p, 8, 64));
      pm[nt][j] = p;
    }
  f16x8 Pf[4];
#pragma unroll
  for (int ks = 0; ks < 4; ks++) Pf[ks] = pack8(pm[2 * ks], pm[2 * ks + 1]);
#pragma unroll
  for (int ks = 0; ks < 4; ks++) {
    Hf0[ks] = pack8(acc[2 * ks][0], acc[2 * ks + 1][0]);
    Hf1[ks] = pack8(acc[2 * ks][1], acc[2 * ks + 1][1]);
  }

  // ---- L3: K=256 = feat + pooled ----
  zero_acc(acc);
#pragma unroll
  for (int ks = 0; ks < 4; ks++) gemm_ks<8>(wtL3, ks, Hf0[ks], Hf1[ks], acc, lane);
#pragma unroll
  for (int ks = 4; ks < 8; ks++) gemm_ks<8>(wtL3, ks, Pf[ks - 4], Pf[ks - 4], acc, lane);
  ln_blk<false>(acc, f2b1, f2g1, f2be1, mf0, mf1, pm, lg);
#pragma unroll
  for (int ks = 0; ks < 4; ks++) {
    Hf0[ks] = pack8(acc[2 * ks][0], acc[2 * ks + 1][0]);
    Hf1[ks] = pack8(acc[2 * ks][1], acc[2 * ks + 1][1]);
  }

  // ---- L4: K=128, mask+pool -> pooled2 ----
  zero_acc(acc);
#pragma unroll
  for (int ks = 0; ks < 4; ks++) gemm_ks<4>(wtL4, ks, Hf0[ks], Hf1[ks], acc, lane);
#pragma unroll
  for (int nt = 0; nt < 8; nt++) pm[nt] = splat4(0.f);
  ln_blk<true>(acc, f2b2, f2g2, f2be2, mf0, mf1, pm, lg);
#pragma unroll
  for (int nt = 0; nt < 8; nt++)
#pragma unroll
    for (int j = 0; j < 4; j++) {
      float p = pm[nt][j];
      p = fmaxf(p, __shfl_xor(p, 1, 64));
      p = fmaxf(p, __shfl_xor(p, 2, 64));
      p = fmaxf(p, __shfl_xor(p, 4, 64));
      p = fmaxf(p, __shfl_xor(p, 8, 64));
      pm[nt][j] = p;
    }

  // ---- emit pooled2 (fp16) + vld; coalesced via per-wave LDS row ----
  if (l15 == 0) {
#pragma unroll
    for (int nt = 0; nt < 8; nt++)
#pragma unroll
      for (int j = 0; j < 4; j++)
        ldsp[w][nt * 16 + 4 * lg + j] = (_Float16)pm[nt][j];
  }
  // same-wave LDS dependency (v7/v8-verified pattern, no barrier)
  const unsigned int pv = *(const unsigned int*)(&ldsp[w][lane * 2]);
  *(unsigned int*)(pooled2h + (size_t)pid * HH + lane * 2) = pv;
  if (lane == 0) vldw[pid] = vld;
}

// ---- k_head (R6/R8-verified) ----
extern "C" __global__ void __launch_bounds__(256, 2)
k_head(const _Float16* __restrict__ pooled2h, const float* __restrict__ vldw,
       const _Float16* __restrict__ wt,
       const float* __restrict__ fob1, const float* __restrict__ fob2,
       float* __restrict__ out)
{
  __shared__ _Float16 Z1[64 * PSTR];
  const int tid = threadIdx.x, lane = tid & 63, w = tid >> 6;
  const int l15 = lane & 15, lg = lane >> 4;
  const int rbase = blockIdx.x * 64;

  const _Float16* FOW1t = wt + 69632;
  const _Float16* FOW2t = wt + 86016;

  {
    f32x4 az[4][2];
    const float bz0 = fob1[32 * w + l15];
    const float bz1 = fob1[32 * w + 16 + l15];
#pragma unroll
    for (int mt = 0; mt < 4; mt++) { az[mt][0] = splat4(bz0); az[mt][1] = splat4(bz1); }
    f16x8 bfr[2][4];
#pragma unroll
    for (int nt = 0; nt < 2; nt++) {
      const _Float16* bp = FOW1t + (size_t)((2 * w + nt) * 16 + l15) * 128 + 4 * lg;
#pragma unroll
      for (int ks = 0; ks < 4; ks++) bfr[nt][ks] = ldfrag2(bp + 32 * ks);
    }
#pragma unroll
    for (int mt = 0; mt < 4; mt++) {
      const _Float16* ap = pooled2h + (size_t)(rbase + mt * 16 + l15) * HH + 4 * lg;
#pragma unroll
      for (int ks = 0; ks < 4; ks++) {
        f16x8 a = ldfrag2(ap + 32 * ks);
        az[mt][0] = MFMA(a, bfr[0][ks], az[mt][0]);
        az[mt][1] = MFMA(a, bfr[1][ks], az[mt][1]);
      }
    }
#pragma unroll
    for (int mt = 0; mt < 4; mt++)
#pragma unroll
      for (int j = 0; j < 4; j++) {
        const int row = mt * 16 + lg * 4 + j;
        Z1[row * PSTR + 32 * w + l15]      = (_Float16)fmaxf(az[mt][0][j], 0.f);
        Z1[row * PSTR + 32 * w + 16 + l15] = (_Float16)fmaxf(az[mt][1][j], 0.f);
      }
  }
  __syncthreads();

  {
    f16x8 a[4][4];
#pragma unroll
    for (int mt = 0; mt < 4; mt++)
#pragma unroll
      for (int ks = 0; ks < 4; ks++)
        a[mt][ks] = ldfrag2(Z1 + (mt * 16 + l15) * PSTR + 4 * lg + 32 * ks);
    f32x4 o[4][4];
#pragma unroll
    for (int nt = 0; nt < 4; nt++) {
      const int c = (4 * w + nt) * 16 + l15;
      const float bo = fob2[c];
#pragma unroll
      for (int mt = 0; mt < 4; mt++) o[mt][nt] = splat4(bo);
      const _Float16* bp = FOW2t + (size_t)((4 * w + nt) * 16 + l15) * 128 + 4 * lg;
#pragma unroll
      for (int ks = 0; ks < 4; ks++) {
        f16x8 b = ldfrag2(bp + 32 * ks);
#pragma unroll
        for (int mt = 0; mt < 4; mt++) o[mt][nt] = MFMA(a[mt][ks], b, o[mt][nt]);
      }
    }
#pragma unroll
    for (int mt = 0; mt < 4; mt++)
#pragma unroll
      for (int j = 0; j < 4; j++) {
        const int row = mt * 16 + lg * 4 + j;
        const float v = vldw[rbase + row];
#pragma unroll
        for (int nt = 0; nt < 4; nt++)
          out[(size_t)(rbase + row) * OO + (4 * w + nt) * 16 + l15] = o[mt][nt][j] * v;
      }
  }
}

extern "C" void kernel_launch(void* const* d_in, const int* in_sizes, int n_in,
                              void* d_out, int out_size, void* d_ws, size_t ws_size,
                              hipStream_t stream)
{
  const float* poly  = (const float*)d_in[0];
  const int*   mask  = (const int*)d_in[1];
  const float* W1    = (const float*)d_in[2];
  const float* b1    = (const float*)d_in[3];
  const float* g1    = (const float*)d_in[4];
  const float* be1   = (const float*)d_in[5];
  const float* W2    = (const float*)d_in[6];
  const float* b2    = (const float*)d_in[7];
  const float* g2    = (const float*)d_in[8];
  const float* be2   = (const float*)d_in[9];
  const float* f2W1  = (const float*)d_in[10];
  const float* f2b1  = (const float*)d_in[11];
  const float* f2g1  = (const float*)d_in[12];
  const float* f2be1 = (const float*)d_in[13];
  const float* f2W2  = (const float*)d_in[14];
  const float* f2b2  = (const float*)d_in[15];
  const float* f2g2  = (const float*)d_in[16];
  const float* f2be2 = (const float*)d_in[17];
  const float* foW1  = (const float*)d_in[18];
  const float* fob1  = (const float*)d_in[19];
  const float* foW2  = (const float*)d_in[20];
  const float* fob2  = (const float*)d_in[21];
  float* out = (float*)d_out;

  const int npoly = in_sizes[0] / (PP * 13);   // 16384

  // ws layout: wt fp16 118784 halves (237,568 B) | pooled2h fp16 npoly*128 | vldw f32 npoly
  char* ws = (char*)d_ws;
  _Float16* wt       = (_Float16*)ws;
  _Float16* pooled2h = (_Float16*)(ws + 237568);
  float*    vldw     = (float*)(ws + 237568 + (size_t)npoly * HH * 2);

  prep_weights<<<dim3((118784 + 255) / 256), dim3(256), 0, stream>>>(
      W1, W2, f2W1, f2W2, foW1, foW2, wt);

  polynet_main<<<dim3(npoly / NW), dim3(1024), 0, stream>>>(
      poly, mask, b1, g1, be1, b2, g2, be2,
      f2b1, f2g1, f2be1, f2b2, f2g2, f2be2,
      wt, pooled2h, vldw);

  k_head<<<dim3(npoly / 64), dim3(256), 0, stream>>>(
      pooled2h, vldw, wt, fob1, fob2, out);
}